// Round 5
// baseline (177.861 us; speedup 1.0000x reference)
//
#include <hip/hip_runtime.h>

// HeteroVGAEEncoder: 2-layer GCN on two independent graphs (disease, gene).
// R5: B-phases were latency-bound (R4 evidence: kB2 dur identical whether data
// came from HBM or L3; VALUBusy 2.4%, 241 GB/s). Fix: 16 records per thread
// via 4 independent uint4 loads + batched gathers (16x deeper MLP), with
// bucket rows sentinel-padded to 16-record boundaries so the inner loop is
// branch-free. Pipeline (from R4): kH per-chunk histograms -> kScan bucket
// scan (+pad) -> kA2 counting-sort scatter (bucket-major records) -> kB1/2/3
// sequential-read + LDS accumulate.
// Algebraic collapse (verified R1-R4): GCN is linear -> propagate 1 (disease)
// / 2 (gene) scalars; fold dinv[dst] out of edge passes; 32-wide MLP node-wise.

static constexpr int N_NODES = 100000;
static constexpr int N_EDGE  = 3200000;
static constexpr int E4      = N_EDGE / 4;

static constexpr int NPB   = 256;                        // nodes per bucket
static constexpr int NBKT  = (N_NODES + NPB - 1) / NPB;  // 391
static constexpr int NBIN  = 392;                        // hist bins (last: 0)
static constexpr int CHUNK = 6400;                       // edges per A-chunk
static constexpr int ABLK  = N_EDGE / CHUNK;             // 500 (exact)
static constexpr int CAP_B = 9216;  // bucket row capacity (mean 8184, sd 90); /16 ok
static constexpr unsigned SRC_MASK = 0x1FFFFu;           // 17 bits
static constexpr unsigned SENTINEL = 256u << 17;         // dl=256, src=0

// ============================== fast path =================================

// ---- kH: per-chunk bucket histogram (counts blk-major, coalesced) ----------
__global__ __launch_bounds__(256) void kH(
    const int* __restrict__ ei_d, const int* __restrict__ ei_g,
    int* __restrict__ tabT)                       // [2][ABLK][NBIN]
{
    __shared__ int hist[NBIN];
    const int g = blockIdx.y, blk = blockIdx.x, t = threadIdx.x;
    const int* dst = (g ? ei_g : ei_d) + N_EDGE + blk * CHUNK;
    for (int i = t; i < NBIN; i += 256) hist[i] = 0;
    __syncthreads();
    for (int e = t * 4; e < CHUNK; e += 1024) {
        int4 d4 = *(const int4*)(dst + e);
        atomicAdd(&hist[d4.x >> 8], 1);
        atomicAdd(&hist[d4.y >> 8], 1);
        atomicAdd(&hist[d4.z >> 8], 1);
        atomicAdd(&hist[d4.w >> 8], 1);
    }
    __syncthreads();
    int* row = tabT + (g * ABLK + blk) * NBIN;
    for (int i = t; i < NBIN; i += 256) row[i] = hist[i];
}

// ---- kScan: per-bucket exclusive scan over chunk counts + sentinel pad -----
__global__ __launch_bounds__(512) void kScan(
    const int* __restrict__ tabT,                 // [2][ABLK][NBIN]
    int* __restrict__ tab,                        // [2][NBKT][ABLK]
    int* __restrict__ bn,                         // [2][NBKT]
    unsigned* __restrict__ recB)                  // [2][NBKT][CAP_B]
{
    __shared__ int sc[512];
    __shared__ int total;
    const int g = blockIdx.y, b = blockIdx.x, t = threadIdx.x;
    int c = 0;
    if (t < ABLK) c = tabT[(g * ABLK + t) * NBIN + b];   // strided; L2-resident
    sc[t] = c;
    __syncthreads();
    for (int d = 1; d < 512; d <<= 1) {
        int add = (t >= d) ? sc[t - d] : 0;
        __syncthreads();
        sc[t] += add;
        __syncthreads();
    }
    if (t < ABLK) tab[(g * NBKT + b) * ABLK + t] = sc[t] - c;  // exclusive
    if (t == 511) { bn[g * NBKT + b] = sc[511]; total = sc[511]; }
    __syncthreads();
    // pad row tail to 16-record boundary with sentinels (branch-free B loops)
    int n = min(total, CAP_B);
    int nv = (n + 15) & ~15;
    if (t < nv - n)
        recB[((size_t)(g * NBKT + b)) * CAP_B + n + t] = SENTINEL;
}

// ---- kA2: per-chunk counting sort, scatter segments to global slots --------
__global__ __launch_bounds__(256) void kA2(
    const int* __restrict__ ei_d, const int* __restrict__ ei_g,
    const int* __restrict__ tab,
    unsigned* __restrict__ recB)                  // [2][NBKT][CAP_B]
{
    __shared__ int hist[NBIN];
    __shared__ int sstart[NBIN];
    __shared__ int offs[NBIN];
    __shared__ int scanbuf[256];
    __shared__ unsigned stage[CHUNK];
    const int g = blockIdx.y, blk = blockIdx.x, t = threadIdx.x;
    const int* src = (g ? ei_g : ei_d) + blk * CHUNK;
    const int* dst = (g ? ei_g : ei_d) + N_EDGE + blk * CHUNK;

    for (int i = t; i < NBIN; i += 256) hist[i] = 0;
    __syncthreads();

    for (int e = t * 4; e < CHUNK; e += 1024) {
        int4 d4 = *(const int4*)(dst + e);
        atomicAdd(&hist[d4.x >> 8], 1);
        atomicAdd(&hist[d4.y >> 8], 1);
        atomicAdd(&hist[d4.z >> 8], 1);
        atomicAdd(&hist[d4.w >> 8], 1);
    }
    __syncthreads();

    int c0 = (2 * t < NBIN) ? hist[2 * t] : 0;
    int c1 = (2 * t + 1 < NBIN) ? hist[2 * t + 1] : 0;
    scanbuf[t] = c0 + c1;
    __syncthreads();
    for (int d = 1; d < 256; d <<= 1) {
        int add = (t >= d) ? scanbuf[t - d] : 0;
        __syncthreads();
        scanbuf[t] += add;
        __syncthreads();
    }
    int excl = t ? scanbuf[t - 1] : 0;
    if (2 * t < NBIN)     { sstart[2 * t] = excl;          offs[2 * t] = excl; }
    if (2 * t + 1 < NBIN) { sstart[2 * t + 1] = excl + c0; offs[2 * t + 1] = excl + c0; }
    __syncthreads();

    for (int e = t * 4; e < CHUNK; e += 1024) {
        int4 s4 = *(const int4*)(src + e);
        int4 d4 = *(const int4*)(dst + e);
        int p;
        p = atomicAdd(&offs[d4.x >> 8], 1);
        stage[p] = ((unsigned)(d4.x & 255) << 17) | (unsigned)s4.x;
        p = atomicAdd(&offs[d4.y >> 8], 1);
        stage[p] = ((unsigned)(d4.y & 255) << 17) | (unsigned)s4.y;
        p = atomicAdd(&offs[d4.z >> 8], 1);
        stage[p] = ((unsigned)(d4.z & 255) << 17) | (unsigned)s4.z;
        p = atomicAdd(&offs[d4.w >> 8], 1);
        stage[p] = ((unsigned)(d4.w & 255) << 17) | (unsigned)s4.w;
    }
    __syncthreads();

    // copy each bucket-segment to its exact global slot (16-lane groups)
    const int grp = t >> 4, ln = t & 15;
    for (int b = grp; b < NBKT; b += 16) {
        int s0 = sstart[b];
        int len = offs[b] - s0;
        if (len == 0) continue;
        int gpos = tab[(g * NBKT + b) * ABLK + blk];
        unsigned* dp = recB + ((size_t)(g * NBKT + b)) * CAP_B + gpos;
        for (int i = ln; i < len; i += 16)
            if (gpos + i < CAP_B) dp[i] = stage[s0 + i];
    }
}

// Helper macro: process 16 records from 4 uint4s
#define LOAD16(q, r)                                                     \
    uint4 r##0 = (q)[0], r##1 = (q)[1], r##2 = (q)[2], r##3 = (q)[3];

// ---- kB1: degree -> dinv, pre-scaled features xs ---------------------------
__global__ __launch_bounds__(512) void kB1(
    const unsigned* __restrict__ recB, const int* __restrict__ bn,
    const float* __restrict__ x_d, const float2* __restrict__ x_g,
    float* __restrict__ dinv_d, float* __restrict__ dinv_g,
    float* __restrict__ xs_d, float2* __restrict__ xs_g)
{
    __shared__ int dcnt[NPB + 1];
    const int g = blockIdx.y, b = blockIdx.x, t = threadIdx.x;
    if (t < NPB + 1) dcnt[t] = 0;
    __syncthreads();
    const int n = min(bn[g * NBKT + b], CAP_B);
    const int ngrp = ((n + 15) & ~15) >> 4;
    const unsigned* p = recB + ((size_t)(g * NBKT + b)) * CAP_B;
    for (int gi = t; gi < ngrp; gi += 512) {
        const uint4* q = (const uint4*)(p + (gi << 4));
        LOAD16(q, r)
        atomicAdd(&dcnt[r0.x >> 17], 1); atomicAdd(&dcnt[r0.y >> 17], 1);
        atomicAdd(&dcnt[r0.z >> 17], 1); atomicAdd(&dcnt[r0.w >> 17], 1);
        atomicAdd(&dcnt[r1.x >> 17], 1); atomicAdd(&dcnt[r1.y >> 17], 1);
        atomicAdd(&dcnt[r1.z >> 17], 1); atomicAdd(&dcnt[r1.w >> 17], 1);
        atomicAdd(&dcnt[r2.x >> 17], 1); atomicAdd(&dcnt[r2.y >> 17], 1);
        atomicAdd(&dcnt[r2.z >> 17], 1); atomicAdd(&dcnt[r2.w >> 17], 1);
        atomicAdd(&dcnt[r3.x >> 17], 1); atomicAdd(&dcnt[r3.y >> 17], 1);
        atomicAdd(&dcnt[r3.z >> 17], 1); atomicAdd(&dcnt[r3.w >> 17], 1);
    }
    __syncthreads();
    const int node = (b << 8) + t;
    if (t < NPB && node < N_NODES) {
        int deg = dcnt[t];
        float v = deg > 0 ? rsqrtf((float)deg) : 0.0f;
        if (g == 0) {
            dinv_d[node] = v;
            xs_d[node] = x_d[node] * v;
        } else {
            dinv_g[node] = v;
            float2 xg = x_g[node];
            xs_g[node] = make_float2(xg.x * v, xg.y * v);
        }
    }
}

// ---- kB2: layer-1 accumulate + node MLP -> tt = t*dinv ---------------------
__global__ __launch_bounds__(512) void kB2(
    const unsigned* __restrict__ recB, const int* __restrict__ bn,
    const float* __restrict__ dinv_d, const float* __restrict__ dinv_g,
    const float* __restrict__ xs_d, const float2* __restrict__ xs_g,
    const float* __restrict__ W1_d, const float* __restrict__ b1_d,
    const float* __restrict__ W2_d,
    const float* __restrict__ W1_g, const float* __restrict__ b1_g,
    const float* __restrict__ W2_g,
    float* __restrict__ tt_d, float* __restrict__ tt_g)
{
    __shared__ float acc[2 * (NPB + 1)];
    const int g = blockIdx.y, b = blockIdx.x, t = threadIdx.x;
    if (t < NPB + 1) { acc[t] = 0.0f; acc[t + NPB + 1] = 0.0f; }
    __syncthreads();
    const int n = min(bn[g * NBKT + b], CAP_B);
    const int ngrp = ((n + 15) & ~15) >> 4;
    const unsigned* p = recB + ((size_t)(g * NBKT + b)) * CAP_B;
    if (g == 0) {
        for (int gi = t; gi < ngrp; gi += 512) {
            const uint4* q = (const uint4*)(p + (gi << 4));
            LOAD16(q, r)
            // batch the 16 independent gathers, then the atomics
            float v0 = xs_d[r0.x & SRC_MASK], v1 = xs_d[r0.y & SRC_MASK];
            float v2 = xs_d[r0.z & SRC_MASK], v3 = xs_d[r0.w & SRC_MASK];
            float v4 = xs_d[r1.x & SRC_MASK], v5 = xs_d[r1.y & SRC_MASK];
            float v6 = xs_d[r1.z & SRC_MASK], v7 = xs_d[r1.w & SRC_MASK];
            float v8 = xs_d[r2.x & SRC_MASK], v9 = xs_d[r2.y & SRC_MASK];
            float va = xs_d[r2.z & SRC_MASK], vb = xs_d[r2.w & SRC_MASK];
            float vc = xs_d[r3.x & SRC_MASK], vd = xs_d[r3.y & SRC_MASK];
            float ve = xs_d[r3.z & SRC_MASK], vf = xs_d[r3.w & SRC_MASK];
            atomicAdd(&acc[r0.x >> 17], v0); atomicAdd(&acc[r0.y >> 17], v1);
            atomicAdd(&acc[r0.z >> 17], v2); atomicAdd(&acc[r0.w >> 17], v3);
            atomicAdd(&acc[r1.x >> 17], v4); atomicAdd(&acc[r1.y >> 17], v5);
            atomicAdd(&acc[r1.z >> 17], v6); atomicAdd(&acc[r1.w >> 17], v7);
            atomicAdd(&acc[r2.x >> 17], v8); atomicAdd(&acc[r2.y >> 17], v9);
            atomicAdd(&acc[r2.z >> 17], va); atomicAdd(&acc[r2.w >> 17], vb);
            atomicAdd(&acc[r3.x >> 17], vc); atomicAdd(&acc[r3.y >> 17], vd);
            atomicAdd(&acc[r3.z >> 17], ve); atomicAdd(&acc[r3.w >> 17], vf);
        }
        __syncthreads();
        const int node = (b << 8) + t;
        if (t < NPB && node < N_NODES) {
            float v = dinv_d[node];
            float s = acc[t] * v;
            float a = 0.0f;
#pragma unroll
            for (int k = 0; k < 32; ++k)
                a += fmaxf(s * W1_d[k] + b1_d[k], 0.0f) * W2_d[k];
            tt_d[node] = a * v;
        }
    } else {
        for (int gi = t; gi < ngrp; gi += 512) {
            const uint4* q = (const uint4*)(p + (gi << 4));
            LOAD16(q, r)
            float2 v0 = xs_g[r0.x & SRC_MASK], v1 = xs_g[r0.y & SRC_MASK];
            float2 v2 = xs_g[r0.z & SRC_MASK], v3 = xs_g[r0.w & SRC_MASK];
            float2 v4 = xs_g[r1.x & SRC_MASK], v5 = xs_g[r1.y & SRC_MASK];
            float2 v6 = xs_g[r1.z & SRC_MASK], v7 = xs_g[r1.w & SRC_MASK];
            float2 v8 = xs_g[r2.x & SRC_MASK], v9 = xs_g[r2.y & SRC_MASK];
            float2 va = xs_g[r2.z & SRC_MASK], vb = xs_g[r2.w & SRC_MASK];
            float2 vc = xs_g[r3.x & SRC_MASK], vd = xs_g[r3.y & SRC_MASK];
            float2 ve = xs_g[r3.z & SRC_MASK], vf = xs_g[r3.w & SRC_MASK];
            atomicAdd(&acc[r0.x >> 17], v0.x); atomicAdd(&acc[(r0.x >> 17) + NPB + 1], v0.y);
            atomicAdd(&acc[r0.y >> 17], v1.x); atomicAdd(&acc[(r0.y >> 17) + NPB + 1], v1.y);
            atomicAdd(&acc[r0.z >> 17], v2.x); atomicAdd(&acc[(r0.z >> 17) + NPB + 1], v2.y);
            atomicAdd(&acc[r0.w >> 17], v3.x); atomicAdd(&acc[(r0.w >> 17) + NPB + 1], v3.y);
            atomicAdd(&acc[r1.x >> 17], v4.x); atomicAdd(&acc[(r1.x >> 17) + NPB + 1], v4.y);
            atomicAdd(&acc[r1.y >> 17], v5.x); atomicAdd(&acc[(r1.y >> 17) + NPB + 1], v5.y);
            atomicAdd(&acc[r1.z >> 17], v6.x); atomicAdd(&acc[(r1.z >> 17) + NPB + 1], v6.y);
            atomicAdd(&acc[r1.w >> 17], v7.x); atomicAdd(&acc[(r1.w >> 17) + NPB + 1], v7.y);
            atomicAdd(&acc[r2.x >> 17], v8.x); atomicAdd(&acc[(r2.x >> 17) + NPB + 1], v8.y);
            atomicAdd(&acc[r2.y >> 17], v9.x); atomicAdd(&acc[(r2.y >> 17) + NPB + 1], v9.y);
            atomicAdd(&acc[r2.z >> 17], va.x); atomicAdd(&acc[(r2.z >> 17) + NPB + 1], va.y);
            atomicAdd(&acc[r2.w >> 17], vb.x); atomicAdd(&acc[(r2.w >> 17) + NPB + 1], vb.y);
            atomicAdd(&acc[r3.x >> 17], vc.x); atomicAdd(&acc[(r3.x >> 17) + NPB + 1], vc.y);
            atomicAdd(&acc[r3.y >> 17], vd.x); atomicAdd(&acc[(r3.y >> 17) + NPB + 1], vd.y);
            atomicAdd(&acc[r3.z >> 17], ve.x); atomicAdd(&acc[(r3.z >> 17) + NPB + 1], ve.y);
            atomicAdd(&acc[r3.w >> 17], vf.x); atomicAdd(&acc[(r3.w >> 17) + NPB + 1], vf.y);
        }
        __syncthreads();
        const int node = (b << 8) + t;
        if (t < NPB && node < N_NODES) {
            float v = dinv_g[node];
            float s0 = acc[t] * v;
            float s1 = acc[t + NPB + 1] * v;
            float a = 0.0f;
#pragma unroll
            for (int k = 0; k < 32; ++k)
                a += fmaxf(s0 * W1_g[k] + s1 * W1_g[32 + k] + b1_g[k], 0.0f) * W2_g[k];
            tt_g[node] = a * v;
        }
    }
}

// ---- kB3: layer-2 accumulate -> out = acc*dinv + b2 ------------------------
__global__ __launch_bounds__(512) void kB3(
    const unsigned* __restrict__ recB, const int* __restrict__ bn,
    const float* __restrict__ dinv_d, const float* __restrict__ dinv_g,
    const float* __restrict__ tt_d, const float* __restrict__ tt_g,
    const float* __restrict__ b2_d, const float* __restrict__ b2_g,
    float* __restrict__ out)
{
    __shared__ float acc[NPB + 1];
    const int g = blockIdx.y, b = blockIdx.x, t = threadIdx.x;
    if (t < NPB + 1) acc[t] = 0.0f;
    __syncthreads();
    const int n = min(bn[g * NBKT + b], CAP_B);
    const int ngrp = ((n + 15) & ~15) >> 4;
    const unsigned* p = recB + ((size_t)(g * NBKT + b)) * CAP_B;
    const float* tt = (g ? tt_g : tt_d);
    for (int gi = t; gi < ngrp; gi += 512) {
        const uint4* q = (const uint4*)(p + (gi << 4));
        LOAD16(q, r)
        float v0 = tt[r0.x & SRC_MASK], v1 = tt[r0.y & SRC_MASK];
        float v2 = tt[r0.z & SRC_MASK], v3 = tt[r0.w & SRC_MASK];
        float v4 = tt[r1.x & SRC_MASK], v5 = tt[r1.y & SRC_MASK];
        float v6 = tt[r1.z & SRC_MASK], v7 = tt[r1.w & SRC_MASK];
        float v8 = tt[r2.x & SRC_MASK], v9 = tt[r2.y & SRC_MASK];
        float va = tt[r2.z & SRC_MASK], vb = tt[r2.w & SRC_MASK];
        float vc = tt[r3.x & SRC_MASK], vd = tt[r3.y & SRC_MASK];
        float ve = tt[r3.z & SRC_MASK], vf = tt[r3.w & SRC_MASK];
        atomicAdd(&acc[r0.x >> 17], v0); atomicAdd(&acc[r0.y >> 17], v1);
        atomicAdd(&acc[r0.z >> 17], v2); atomicAdd(&acc[r0.w >> 17], v3);
        atomicAdd(&acc[r1.x >> 17], v4); atomicAdd(&acc[r1.y >> 17], v5);
        atomicAdd(&acc[r1.z >> 17], v6); atomicAdd(&acc[r1.w >> 17], v7);
        atomicAdd(&acc[r2.x >> 17], v8); atomicAdd(&acc[r2.y >> 17], v9);
        atomicAdd(&acc[r2.z >> 17], va); atomicAdd(&acc[r2.w >> 17], vb);
        atomicAdd(&acc[r3.x >> 17], vc); atomicAdd(&acc[r3.y >> 17], vd);
        atomicAdd(&acc[r3.z >> 17], ve); atomicAdd(&acc[r3.w >> 17], vf);
    }
    __syncthreads();
    const int node = (b << 8) + t;
    if (t < NPB && node < N_NODES) {
        float v = (g ? dinv_g : dinv_d)[node];
        float bias = (g ? b2_g : b2_d)[0];
        out[g * N_NODES + node] = acc[t] * v + bias;
    }
}

// ============================ fallback path (R1) ===========================

__global__ __launch_bounds__(256) void k_deg(
    const int4* __restrict__ dst_d, const int4* __restrict__ dst_g,
    float* __restrict__ deg_d, float* __restrict__ deg_g)
{
    int tid = blockIdx.x * 256 + threadIdx.x;
    int stride = gridDim.x * 256;
    for (int e = tid; e < E4; e += stride) {
        int4 a = dst_d[e];
        int4 b = dst_g[e];
        atomicAdd(&deg_d[a.x], 1.0f); atomicAdd(&deg_d[a.y], 1.0f);
        atomicAdd(&deg_d[a.z], 1.0f); atomicAdd(&deg_d[a.w], 1.0f);
        atomicAdd(&deg_g[b.x], 1.0f); atomicAdd(&deg_g[b.y], 1.0f);
        atomicAdd(&deg_g[b.z], 1.0f); atomicAdd(&deg_g[b.w], 1.0f);
    }
}

__global__ __launch_bounds__(256) void k_dinv(
    float* __restrict__ dinv_d, float* __restrict__ dinv_g,
    const float* __restrict__ x_d, const float2* __restrict__ x_g,
    float* __restrict__ xs_d, float2* __restrict__ xs_g)
{
    int i = blockIdx.x * 256 + threadIdx.x;
    int stride = gridDim.x * 256;
    for (; i < N_NODES; i += stride) {
        float dd = dinv_d[i];
        float vd = dd > 0.0f ? rsqrtf(dd) : 0.0f;
        dinv_d[i] = vd;
        xs_d[i] = x_d[i] * vd;
        float dg = dinv_g[i];
        float vg = dg > 0.0f ? rsqrtf(dg) : 0.0f;
        dinv_g[i] = vg;
        float2 xg = x_g[i];
        xs_g[i] = make_float2(xg.x * vg, xg.y * vg);
    }
}

__global__ __launch_bounds__(256) void k_prop1(
    const int4* __restrict__ src_d, const int4* __restrict__ dst_d,
    const int4* __restrict__ src_g, const int4* __restrict__ dst_g,
    const float* __restrict__ xs_d, const float2* __restrict__ xs_g,
    float* __restrict__ s_d, float2* __restrict__ s_g)
{
    int tid = blockIdx.x * 256 + threadIdx.x;
    int stride = gridDim.x * 256;
    for (int e = tid; e < E4; e += stride) {
        int4 sa = src_d[e]; int4 da = dst_d[e];
        int4 sb = src_g[e]; int4 db = dst_g[e];
        atomicAdd(&s_d[da.x], xs_d[sa.x]);
        atomicAdd(&s_d[da.y], xs_d[sa.y]);
        atomicAdd(&s_d[da.z], xs_d[sa.z]);
        atomicAdd(&s_d[da.w], xs_d[sa.w]);
        float2 g0 = xs_g[sb.x]; float2 g1 = xs_g[sb.y];
        float2 g2 = xs_g[sb.z]; float2 g3 = xs_g[sb.w];
        atomicAdd(&s_g[db.x].x, g0.x); atomicAdd(&s_g[db.x].y, g0.y);
        atomicAdd(&s_g[db.y].x, g1.x); atomicAdd(&s_g[db.y].y, g1.y);
        atomicAdd(&s_g[db.z].x, g2.x); atomicAdd(&s_g[db.z].y, g2.y);
        atomicAdd(&s_g[db.w].x, g3.x); atomicAdd(&s_g[db.w].y, g3.y);
    }
}

__global__ __launch_bounds__(256) void k_node(
    const float* __restrict__ dinv_d, const float* __restrict__ dinv_g,
    float* s_d, float2* s_g,
    const float* __restrict__ W1_d, const float* __restrict__ b1_d,
    const float* __restrict__ W2_d,
    const float* __restrict__ W1_g, const float* __restrict__ b1_g,
    const float* __restrict__ W2_g)
{
    int i = blockIdx.x * 256 + threadIdx.x;
    int stride = gridDim.x * 256;
    for (; i < N_NODES; i += stride) {
        float vd = dinv_d[i];
        float sd = s_d[i] * vd;
        float acc_d = 0.0f;
#pragma unroll
        for (int k = 0; k < 32; ++k)
            acc_d += fmaxf(sd * W1_d[k] + b1_d[k], 0.0f) * W2_d[k];
        s_d[i] = acc_d * vd;
        float vg = dinv_g[i];
        float2 sg = s_g[i];
        float s0 = sg.x * vg;
        float s1 = sg.y * vg;
        float acc_g = 0.0f;
#pragma unroll
        for (int k = 0; k < 32; ++k)
            acc_g += fmaxf(s0 * W1_g[k] + s1 * W1_g[32 + k] + b1_g[k], 0.0f) * W2_g[k];
        s_g[i].x = acc_g * vg;
    }
}

__global__ __launch_bounds__(256) void k_prop2(
    const int4* __restrict__ src_d, const int4* __restrict__ dst_d,
    const int4* __restrict__ src_g, const int4* __restrict__ dst_g,
    const float* __restrict__ tt_d, const float* __restrict__ tt_g2,
    float* __restrict__ out)
{
    int tid = blockIdx.x * 256 + threadIdx.x;
    int stride = gridDim.x * 256;
    for (int e = tid; e < E4; e += stride) {
        int4 sa = src_d[e]; int4 da = dst_d[e];
        int4 sb = src_g[e]; int4 db = dst_g[e];
        atomicAdd(&out[da.x], tt_d[sa.x]);
        atomicAdd(&out[da.y], tt_d[sa.y]);
        atomicAdd(&out[da.z], tt_d[sa.z]);
        atomicAdd(&out[da.w], tt_d[sa.w]);
        atomicAdd(&out[N_NODES + db.x], tt_g2[2 * sb.x]);
        atomicAdd(&out[N_NODES + db.y], tt_g2[2 * sb.y]);
        atomicAdd(&out[N_NODES + db.z], tt_g2[2 * sb.z]);
        atomicAdd(&out[N_NODES + db.w], tt_g2[2 * sb.w]);
    }
}

__global__ __launch_bounds__(256) void k_final(
    float* __restrict__ out,
    const float* __restrict__ dinv_d, const float* __restrict__ dinv_g,
    const float* __restrict__ b2_d, const float* __restrict__ b2_g)
{
    int i = blockIdx.x * 256 + threadIdx.x;
    int stride = gridDim.x * 256;
    float bd = b2_d[0];
    float bg = b2_g[0];
    for (; i < N_NODES; i += stride) {
        out[i] = out[i] * dinv_d[i] + bd;
        out[N_NODES + i] = out[N_NODES + i] * dinv_g[i] + bg;
    }
}

// ================================ launch ===================================

extern "C" void kernel_launch(void* const* d_in, const int* in_sizes, int n_in,
                              void* d_out, int out_size, void* d_ws, size_t ws_size,
                              hipStream_t stream) {
    const float* x_d  = (const float*)d_in[0];
    const float* x_g  = (const float*)d_in[1];
    const int*   ei_d = (const int*)d_in[2];
    const int*   ei_g = (const int*)d_in[3];
    const float* W1_d = (const float*)d_in[4];
    const float* b1_d = (const float*)d_in[5];
    const float* W1_g = (const float*)d_in[6];
    const float* b1_g = (const float*)d_in[7];
    const float* W2_d = (const float*)d_in[8];
    const float* b2_d = (const float*)d_in[9];
    const float* W2_g = (const float*)d_in[10];
    const float* b2_g = (const float*)d_in[11];
    float* out = (float*)d_out;

    // fast-path workspace layout (4B words)
    const size_t RECB_W = (size_t)2 * NBKT * CAP_B;   // 7,206,912
    const size_t NODE_W = (size_t)7 * N_NODES;        //   700,000
    const size_t TABT_W = (size_t)2 * ABLK * NBIN;    //   392,000
    const size_t TAB_W  = (size_t)2 * NBKT * ABLK;    //   391,000
    const size_t BN_W   = (size_t)2 * NBKT;           //       782
    const size_t need   = RECB_W + NODE_W + TABT_W + TAB_W + BN_W; // 34.76 MB

    if (ws_size >= need * 4) {
        unsigned* recB = (unsigned*)d_ws;
        float* fws    = (float*)d_ws + RECB_W;
        float* dinv_d = fws;
        float* dinv_g = fws + 1 * N_NODES;
        float* xs_d   = fws + 2 * N_NODES;
        float* xs_g   = fws + 3 * N_NODES;            // [2N] float2
        float* tt_d   = fws + 5 * N_NODES;
        float* tt_g   = fws + 6 * N_NODES;
        int* tabT = (int*)d_ws + RECB_W + NODE_W;
        int* tab  = tabT + TABT_W;
        int* bn   = tab + TAB_W;

        dim3 gA(ABLK, 2), gS(NBKT, 2), gB(NBKT, 2);
        kH   <<<gA, 256, 0, stream>>>(ei_d, ei_g, tabT);
        kScan<<<gS, 512, 0, stream>>>(tabT, tab, bn, recB);
        kA2  <<<gA, 256, 0, stream>>>(ei_d, ei_g, tab, recB);
        kB1  <<<gB, 512, 0, stream>>>(recB, bn, x_d, (const float2*)x_g,
                                      dinv_d, dinv_g, xs_d, (float2*)xs_g);
        kB2  <<<gB, 512, 0, stream>>>(recB, bn, dinv_d, dinv_g,
                                      xs_d, (const float2*)xs_g,
                                      W1_d, b1_d, W2_d, W1_g, b1_g, W2_g,
                                      tt_d, tt_g);
        kB3  <<<gB, 512, 0, stream>>>(recB, bn, dinv_d, dinv_g, tt_d, tt_g,
                                      b2_d, b2_g, out);
        return;
    }

    // fallback: R1 scattered-atomic path (correct, slower)
    const int* src_d = ei_d;
    const int* dst_d = ei_d + N_EDGE;
    const int* src_g = ei_g;
    const int* dst_g = ei_g + N_EDGE;

    float* ws     = (float*)d_ws;
    float* dinv_d = ws;
    float* dinv_g = ws + 1 * N_NODES;
    float* s_d    = ws + 2 * N_NODES;
    float* s_g    = ws + 3 * N_NODES;
    float* xs_d   = ws + 5 * N_NODES;
    float* xs_g   = ws + 6 * N_NODES;

    hipMemsetAsync(ws, 0, (size_t)5 * N_NODES * sizeof(float), stream);
    hipMemsetAsync(d_out, 0, (size_t)2 * N_NODES * sizeof(float), stream);

    const int EB = (E4 + 255) / 256;
    const int NB = (N_NODES + 255) / 256;

    k_deg<<<EB, 256, 0, stream>>>((const int4*)dst_d, (const int4*)dst_g,
                                  dinv_d, dinv_g);
    k_dinv<<<NB, 256, 0, stream>>>(dinv_d, dinv_g, x_d, (const float2*)x_g,
                                   xs_d, (float2*)xs_g);
    k_prop1<<<EB, 256, 0, stream>>>((const int4*)src_d, (const int4*)dst_d,
                                    (const int4*)src_g, (const int4*)dst_g,
                                    xs_d, (const float2*)xs_g,
                                    s_d, (float2*)s_g);
    k_node<<<NB, 256, 0, stream>>>(dinv_d, dinv_g, s_d, (float2*)s_g,
                                   W1_d, b1_d, W2_d, W1_g, b1_g, W2_g);
    k_prop2<<<EB, 256, 0, stream>>>((const int4*)src_d, (const int4*)dst_d,
                                    (const int4*)src_g, (const int4*)dst_g,
                                    s_d, s_g, out);
    k_final<<<NB, 256, 0, stream>>>(out, dinv_d, dinv_g, b2_d, b2_g);
}

// Round 6
// 152.135 us; speedup vs baseline: 1.1691x; 1.1691x over previous
//
#include <hip/hip_runtime.h>

// HeteroVGAEEncoder: 2-layer GCN on two independent graphs (disease, gene).
// R6: full two-level counting sort -> per-node CSR segments. Prop passes are
// one-thread-per-node with ZERO atomics and ZERO LDS (pure sequential reads +
// independent gathers). R5 falsified the latency-chain theory (16x ILP gave
// no speedup); cross-kernel arithmetic says the gather+LDS-atomic interleave
// is the serialized resource. This round separates them into disjoint kernels.
//   kH:     per-chunk bucket histogram (391 buckets of 256 nodes)
//   kScan:  per-bucket scan over chunk counts -> kA2 scatter offsets
//   kA2:    per-chunk counting sort -> bucket-major record rows
//   kSort2: per-row counting sort by node -> sorted rows + np[] CSR + dinv/xs
//   kP1:    per-node gather-sum + MLP -> tt
//   kP2:    per-node gather-sum -> out
// Algebraic collapse (verified R1-R5): GCN is linear -> propagate 1 (disease)
// / 2 (gene) scalars; fold dinv[dst] out of edge passes; 32-wide MLP node-wise.

static constexpr int N_NODES = 100000;
static constexpr int N_EDGE  = 3200000;
static constexpr int E4      = N_EDGE / 4;

static constexpr int NPB   = 256;                        // nodes per bucket
static constexpr int NBKT  = (N_NODES + NPB - 1) / NPB;  // 391
static constexpr int NBIN  = 392;                        // hist bins (last: 0)
static constexpr int CHUNK = 6400;                       // edges per A-chunk
static constexpr int ABLK  = N_EDGE / CHUNK;             // 500 (exact)
static constexpr int CAP_B = 9216;  // bucket row capacity (mean 8184, sd 90)
static constexpr unsigned SRC_MASK = 0x1FFFFu;           // 17 bits

// ============================== fast path =================================

// ---- kH: per-chunk bucket histogram (counts blk-major, coalesced) ----------
__global__ __launch_bounds__(256) void kH(
    const int* __restrict__ ei_d, const int* __restrict__ ei_g,
    int* __restrict__ tabT)                       // [2][ABLK][NBIN]
{
    __shared__ int hist[NBIN];
    const int g = blockIdx.y, blk = blockIdx.x, t = threadIdx.x;
    const int* dst = (g ? ei_g : ei_d) + N_EDGE + blk * CHUNK;
    for (int i = t; i < NBIN; i += 256) hist[i] = 0;
    __syncthreads();
    for (int e = t * 4; e < CHUNK; e += 1024) {
        int4 d4 = *(const int4*)(dst + e);
        atomicAdd(&hist[d4.x >> 8], 1);
        atomicAdd(&hist[d4.y >> 8], 1);
        atomicAdd(&hist[d4.z >> 8], 1);
        atomicAdd(&hist[d4.w >> 8], 1);
    }
    __syncthreads();
    int* row = tabT + (g * ABLK + blk) * NBIN;
    for (int i = t; i < NBIN; i += 256) row[i] = hist[i];
}

// ---- kScan: per-bucket exclusive scan over chunk counts --------------------
__global__ __launch_bounds__(512) void kScan(
    const int* __restrict__ tabT,                 // [2][ABLK][NBIN]
    int* __restrict__ tab,                        // [2][NBKT][ABLK]
    int* __restrict__ bn)                         // [2][NBKT]
{
    __shared__ int sc[512];
    const int g = blockIdx.y, b = blockIdx.x, t = threadIdx.x;
    int c = 0;
    if (t < ABLK) c = tabT[(g * ABLK + t) * NBIN + b];   // strided; L2-resident
    sc[t] = c;
    __syncthreads();
    for (int d = 1; d < 512; d <<= 1) {
        int add = (t >= d) ? sc[t - d] : 0;
        __syncthreads();
        sc[t] += add;
        __syncthreads();
    }
    if (t < ABLK) tab[(g * NBKT + b) * ABLK + t] = sc[t] - c;  // exclusive
    if (t == 511) bn[g * NBKT + b] = sc[511];
}

// ---- kA2: per-chunk counting sort, scatter segments to global slots --------
__global__ __launch_bounds__(256) void kA2(
    const int* __restrict__ ei_d, const int* __restrict__ ei_g,
    const int* __restrict__ tab,
    unsigned* __restrict__ recB)                  // [2][NBKT][CAP_B]
{
    __shared__ int hist[NBIN];
    __shared__ int sstart[NBIN];
    __shared__ int offs[NBIN];
    __shared__ int scanbuf[256];
    __shared__ unsigned stage[CHUNK];
    const int g = blockIdx.y, blk = blockIdx.x, t = threadIdx.x;
    const int* src = (g ? ei_g : ei_d) + blk * CHUNK;
    const int* dst = (g ? ei_g : ei_d) + N_EDGE + blk * CHUNK;

    for (int i = t; i < NBIN; i += 256) hist[i] = 0;
    __syncthreads();

    for (int e = t * 4; e < CHUNK; e += 1024) {
        int4 d4 = *(const int4*)(dst + e);
        atomicAdd(&hist[d4.x >> 8], 1);
        atomicAdd(&hist[d4.y >> 8], 1);
        atomicAdd(&hist[d4.z >> 8], 1);
        atomicAdd(&hist[d4.w >> 8], 1);
    }
    __syncthreads();

    int c0 = (2 * t < NBIN) ? hist[2 * t] : 0;
    int c1 = (2 * t + 1 < NBIN) ? hist[2 * t + 1] : 0;
    scanbuf[t] = c0 + c1;
    __syncthreads();
    for (int d = 1; d < 256; d <<= 1) {
        int add = (t >= d) ? scanbuf[t - d] : 0;
        __syncthreads();
        scanbuf[t] += add;
        __syncthreads();
    }
    int excl = t ? scanbuf[t - 1] : 0;
    if (2 * t < NBIN)     { sstart[2 * t] = excl;          offs[2 * t] = excl; }
    if (2 * t + 1 < NBIN) { sstart[2 * t + 1] = excl + c0; offs[2 * t + 1] = excl + c0; }
    __syncthreads();

    for (int e = t * 4; e < CHUNK; e += 1024) {
        int4 s4 = *(const int4*)(src + e);
        int4 d4 = *(const int4*)(dst + e);
        int p;
        p = atomicAdd(&offs[d4.x >> 8], 1);
        stage[p] = ((unsigned)(d4.x & 255) << 17) | (unsigned)s4.x;
        p = atomicAdd(&offs[d4.y >> 8], 1);
        stage[p] = ((unsigned)(d4.y & 255) << 17) | (unsigned)s4.y;
        p = atomicAdd(&offs[d4.z >> 8], 1);
        stage[p] = ((unsigned)(d4.z & 255) << 17) | (unsigned)s4.z;
        p = atomicAdd(&offs[d4.w >> 8], 1);
        stage[p] = ((unsigned)(d4.w & 255) << 17) | (unsigned)s4.w;
    }
    __syncthreads();

    // copy each bucket-segment to its exact global slot (16-lane groups)
    const int grp = t >> 4, ln = t & 15;
    for (int b = grp; b < NBKT; b += 16) {
        int s0 = sstart[b];
        int len = offs[b] - s0;
        if (len == 0) continue;
        int gpos = tab[(g * NBKT + b) * ABLK + blk];
        unsigned* dp = recB + ((size_t)(g * NBKT + b)) * CAP_B + gpos;
        for (int i = ln; i < len; i += 16)
            if (gpos + i < CAP_B) dp[i] = stage[s0 + i];
    }
}

// ---- kSort2: sort row by node, emit CSR offsets + dinv + xs ----------------
__global__ __launch_bounds__(512) void kSort2(
    unsigned* __restrict__ recB, const int* __restrict__ bn,
    int* __restrict__ np,                         // [2][NBKT][257]
    const float* __restrict__ x_d, const float2* __restrict__ x_g,
    float* __restrict__ dinv_d, float* __restrict__ dinv_g,
    float* __restrict__ xs_d, float2* __restrict__ xs_g)
{
    __shared__ int h2[256];
    __shared__ int sc[512];
    __shared__ int cur[256];
    __shared__ unsigned stg[CAP_B];
    const int g = blockIdx.y, b = blockIdx.x, t = threadIdx.x;
    if (t < 256) h2[t] = 0;
    __syncthreads();
    const int rowi = g * NBKT + b;
    unsigned* row = recB + (size_t)rowi * CAP_B;
    const int n = min(bn[rowi], CAP_B);

    for (int i = t; i < n; i += 512)
        atomicAdd(&h2[(row[i] >> 17) & 255], 1);
    __syncthreads();

    int c = (t < 256) ? h2[t] : 0;
    sc[t] = c;
    __syncthreads();
    for (int d = 1; d < 256; d <<= 1) {
        int add = (t >= d) ? sc[t - d] : 0;
        __syncthreads();
        sc[t] += add;
        __syncthreads();
    }
    if (t < 256) {
        int excl = sc[t] - c;
        cur[t] = excl;
        np[rowi * 257 + t] = excl;
    }
    if (t == 0) np[rowi * 257 + 256] = n;
    __syncthreads();

    for (int i = t; i < n; i += 512) {
        unsigned r = row[i];
        int p = atomicAdd(&cur[(r >> 17) & 255], 1);
        stg[p] = r;
    }
    __syncthreads();
    for (int i = t; i < n; i += 512) row[i] = stg[i];

    // epilogue: degree is h2[t] -> dinv, pre-scaled features
    if (t < 256) {
        int node = (b << 8) + t;
        if (node < N_NODES) {
            int deg = h2[t];
            float v = deg > 0 ? rsqrtf((float)deg) : 0.0f;
            if (g == 0) {
                dinv_d[node] = v;
                xs_d[node] = x_d[node] * v;
            } else {
                dinv_g[node] = v;
                float2 xg = x_g[node];
                xs_g[node] = make_float2(xg.x * v, xg.y * v);
            }
        }
    }
}

// ---- kP1: per-node gather-sum + MLP -> tt = mlp(s*dinv)*dinv ---------------
__global__ __launch_bounds__(256) void kP1(
    const unsigned* __restrict__ recB, const int* __restrict__ np,
    const float* __restrict__ dinv_d, const float* __restrict__ dinv_g,
    const float* __restrict__ xs_d, const float2* __restrict__ xs_g,
    const float* __restrict__ W1_d, const float* __restrict__ b1_d,
    const float* __restrict__ W2_d,
    const float* __restrict__ W1_g, const float* __restrict__ b1_g,
    const float* __restrict__ W2_g,
    float* __restrict__ tt_d, float* __restrict__ tt_g)
{
    const int g = blockIdx.y;
    const int node = blockIdx.x * 256 + threadIdx.x;
    if (node >= N_NODES) return;
    const int b = node >> 8, l = node & 255;
    const int rowi = g * NBKT + b;
    const unsigned* row = recB + (size_t)rowi * CAP_B;
    const int s = np[rowi * 257 + l];
    const int e = np[rowi * 257 + l + 1];
    if (g == 0) {
        float s0 = 0.0f, s1 = 0.0f, s2 = 0.0f, s3 = 0.0f;
        int i = s;
        for (; i + 3 < e; i += 4) {
            s0 += xs_d[row[i]     & SRC_MASK];
            s1 += xs_d[row[i + 1] & SRC_MASK];
            s2 += xs_d[row[i + 2] & SRC_MASK];
            s3 += xs_d[row[i + 3] & SRC_MASK];
        }
        for (; i < e; ++i) s0 += xs_d[row[i] & SRC_MASK];
        float v = dinv_d[node];
        float sf = ((s0 + s1) + (s2 + s3)) * v;
        float a = 0.0f;
#pragma unroll
        for (int k = 0; k < 32; ++k)
            a += fmaxf(sf * W1_d[k] + b1_d[k], 0.0f) * W2_d[k];
        tt_d[node] = a * v;
    } else {
        float x0 = 0.0f, x1 = 0.0f, y0 = 0.0f, y1 = 0.0f;
        int i = s;
        for (; i + 1 < e; i += 2) {
            float2 a0 = xs_g[row[i]     & SRC_MASK];
            float2 a1 = xs_g[row[i + 1] & SRC_MASK];
            x0 += a0.x; y0 += a0.y;
            x1 += a1.x; y1 += a1.y;
        }
        if (i < e) { float2 a0 = xs_g[row[i] & SRC_MASK]; x0 += a0.x; y0 += a0.y; }
        float v = dinv_g[node];
        float sf0 = (x0 + x1) * v;
        float sf1 = (y0 + y1) * v;
        float a = 0.0f;
#pragma unroll
        for (int k = 0; k < 32; ++k)
            a += fmaxf(sf0 * W1_g[k] + sf1 * W1_g[32 + k] + b1_g[k], 0.0f) * W2_g[k];
        tt_g[node] = a * v;
    }
}

// ---- kP2: per-node gather-sum -> out = sum*dinv + b2 -----------------------
__global__ __launch_bounds__(256) void kP2(
    const unsigned* __restrict__ recB, const int* __restrict__ np,
    const float* __restrict__ dinv_d, const float* __restrict__ dinv_g,
    const float* __restrict__ tt_d, const float* __restrict__ tt_g,
    const float* __restrict__ b2_d, const float* __restrict__ b2_g,
    float* __restrict__ out)
{
    const int g = blockIdx.y;
    const int node = blockIdx.x * 256 + threadIdx.x;
    if (node >= N_NODES) return;
    const int b = node >> 8, l = node & 255;
    const int rowi = g * NBKT + b;
    const unsigned* row = recB + (size_t)rowi * CAP_B;
    const int s = np[rowi * 257 + l];
    const int e = np[rowi * 257 + l + 1];
    const float* tt = (g ? tt_g : tt_d);
    float s0 = 0.0f, s1 = 0.0f, s2 = 0.0f, s3 = 0.0f;
    int i = s;
    for (; i + 3 < e; i += 4) {
        s0 += tt[row[i]     & SRC_MASK];
        s1 += tt[row[i + 1] & SRC_MASK];
        s2 += tt[row[i + 2] & SRC_MASK];
        s3 += tt[row[i + 3] & SRC_MASK];
    }
    for (; i < e; ++i) s0 += tt[row[i] & SRC_MASK];
    float v = (g ? dinv_g : dinv_d)[node];
    float bias = (g ? b2_g : b2_d)[0];
    out[g * N_NODES + node] = ((s0 + s1) + (s2 + s3)) * v + bias;
}

// ============================ fallback path (R1) ===========================

__global__ __launch_bounds__(256) void k_deg(
    const int4* __restrict__ dst_d, const int4* __restrict__ dst_g,
    float* __restrict__ deg_d, float* __restrict__ deg_g)
{
    int tid = blockIdx.x * 256 + threadIdx.x;
    int stride = gridDim.x * 256;
    for (int e = tid; e < E4; e += stride) {
        int4 a = dst_d[e];
        int4 b = dst_g[e];
        atomicAdd(&deg_d[a.x], 1.0f); atomicAdd(&deg_d[a.y], 1.0f);
        atomicAdd(&deg_d[a.z], 1.0f); atomicAdd(&deg_d[a.w], 1.0f);
        atomicAdd(&deg_g[b.x], 1.0f); atomicAdd(&deg_g[b.y], 1.0f);
        atomicAdd(&deg_g[b.z], 1.0f); atomicAdd(&deg_g[b.w], 1.0f);
    }
}

__global__ __launch_bounds__(256) void k_dinv(
    float* __restrict__ dinv_d, float* __restrict__ dinv_g,
    const float* __restrict__ x_d, const float2* __restrict__ x_g,
    float* __restrict__ xs_d, float2* __restrict__ xs_g)
{
    int i = blockIdx.x * 256 + threadIdx.x;
    int stride = gridDim.x * 256;
    for (; i < N_NODES; i += stride) {
        float dd = dinv_d[i];
        float vd = dd > 0.0f ? rsqrtf(dd) : 0.0f;
        dinv_d[i] = vd;
        xs_d[i] = x_d[i] * vd;
        float dg = dinv_g[i];
        float vg = dg > 0.0f ? rsqrtf(dg) : 0.0f;
        dinv_g[i] = vg;
        float2 xg = x_g[i];
        xs_g[i] = make_float2(xg.x * vg, xg.y * vg);
    }
}

__global__ __launch_bounds__(256) void k_prop1(
    const int4* __restrict__ src_d, const int4* __restrict__ dst_d,
    const int4* __restrict__ src_g, const int4* __restrict__ dst_g,
    const float* __restrict__ xs_d, const float2* __restrict__ xs_g,
    float* __restrict__ s_d, float2* __restrict__ s_g)
{
    int tid = blockIdx.x * 256 + threadIdx.x;
    int stride = gridDim.x * 256;
    for (int e = tid; e < E4; e += stride) {
        int4 sa = src_d[e]; int4 da = dst_d[e];
        int4 sb = src_g[e]; int4 db = dst_g[e];
        atomicAdd(&s_d[da.x], xs_d[sa.x]);
        atomicAdd(&s_d[da.y], xs_d[sa.y]);
        atomicAdd(&s_d[da.z], xs_d[sa.z]);
        atomicAdd(&s_d[da.w], xs_d[sa.w]);
        float2 g0 = xs_g[sb.x]; float2 g1 = xs_g[sb.y];
        float2 g2 = xs_g[sb.z]; float2 g3 = xs_g[sb.w];
        atomicAdd(&s_g[db.x].x, g0.x); atomicAdd(&s_g[db.x].y, g0.y);
        atomicAdd(&s_g[db.y].x, g1.x); atomicAdd(&s_g[db.y].y, g1.y);
        atomicAdd(&s_g[db.z].x, g2.x); atomicAdd(&s_g[db.z].y, g2.y);
        atomicAdd(&s_g[db.w].x, g3.x); atomicAdd(&s_g[db.w].y, g3.y);
    }
}

__global__ __launch_bounds__(256) void k_node(
    const float* __restrict__ dinv_d, const float* __restrict__ dinv_g,
    float* s_d, float2* s_g,
    const float* __restrict__ W1_d, const float* __restrict__ b1_d,
    const float* __restrict__ W2_d,
    const float* __restrict__ W1_g, const float* __restrict__ b1_g,
    const float* __restrict__ W2_g)
{
    int i = blockIdx.x * 256 + threadIdx.x;
    int stride = gridDim.x * 256;
    for (; i < N_NODES; i += stride) {
        float vd = dinv_d[i];
        float sd = s_d[i] * vd;
        float acc_d = 0.0f;
#pragma unroll
        for (int k = 0; k < 32; ++k)
            acc_d += fmaxf(sd * W1_d[k] + b1_d[k], 0.0f) * W2_d[k];
        s_d[i] = acc_d * vd;
        float vg = dinv_g[i];
        float2 sg = s_g[i];
        float s0 = sg.x * vg;
        float s1 = sg.y * vg;
        float acc_g = 0.0f;
#pragma unroll
        for (int k = 0; k < 32; ++k)
            acc_g += fmaxf(s0 * W1_g[k] + s1 * W1_g[32 + k] + b1_g[k], 0.0f) * W2_g[k];
        s_g[i].x = acc_g * vg;
    }
}

__global__ __launch_bounds__(256) void k_prop2(
    const int4* __restrict__ src_d, const int4* __restrict__ dst_d,
    const int4* __restrict__ src_g, const int4* __restrict__ dst_g,
    const float* __restrict__ tt_d, const float* __restrict__ tt_g2,
    float* __restrict__ out)
{
    int tid = blockIdx.x * 256 + threadIdx.x;
    int stride = gridDim.x * 256;
    for (int e = tid; e < E4; e += stride) {
        int4 sa = src_d[e]; int4 da = dst_d[e];
        int4 sb = src_g[e]; int4 db = dst_g[e];
        atomicAdd(&out[da.x], tt_d[sa.x]);
        atomicAdd(&out[da.y], tt_d[sa.y]);
        atomicAdd(&out[da.z], tt_d[sa.z]);
        atomicAdd(&out[da.w], tt_d[sa.w]);
        atomicAdd(&out[N_NODES + db.x], tt_g2[2 * sb.x]);
        atomicAdd(&out[N_NODES + db.y], tt_g2[2 * sb.y]);
        atomicAdd(&out[N_NODES + db.z], tt_g2[2 * sb.z]);
        atomicAdd(&out[N_NODES + db.w], tt_g2[2 * sb.w]);
    }
}

__global__ __launch_bounds__(256) void k_final(
    float* __restrict__ out,
    const float* __restrict__ dinv_d, const float* __restrict__ dinv_g,
    const float* __restrict__ b2_d, const float* __restrict__ b2_g)
{
    int i = blockIdx.x * 256 + threadIdx.x;
    int stride = gridDim.x * 256;
    float bd = b2_d[0];
    float bg = b2_g[0];
    for (; i < N_NODES; i += stride) {
        out[i] = out[i] * dinv_d[i] + bd;
        out[N_NODES + i] = out[N_NODES + i] * dinv_g[i] + bg;
    }
}

// ================================ launch ===================================

extern "C" void kernel_launch(void* const* d_in, const int* in_sizes, int n_in,
                              void* d_out, int out_size, void* d_ws, size_t ws_size,
                              hipStream_t stream) {
    const float* x_d  = (const float*)d_in[0];
    const float* x_g  = (const float*)d_in[1];
    const int*   ei_d = (const int*)d_in[2];
    const int*   ei_g = (const int*)d_in[3];
    const float* W1_d = (const float*)d_in[4];
    const float* b1_d = (const float*)d_in[5];
    const float* W1_g = (const float*)d_in[6];
    const float* b1_g = (const float*)d_in[7];
    const float* W2_d = (const float*)d_in[8];
    const float* b2_d = (const float*)d_in[9];
    const float* W2_g = (const float*)d_in[10];
    const float* b2_g = (const float*)d_in[11];
    float* out = (float*)d_out;

    // fast-path workspace layout (4B words); np ALIASES tabT (dead after kScan)
    const size_t RECB_W = (size_t)2 * NBKT * CAP_B;   // 7,206,912
    const size_t NODE_W = (size_t)7 * N_NODES;        //   700,000
    const size_t TABT_W = (size_t)2 * ABLK * NBIN;    //   392,000 (np: 200,974)
    const size_t TAB_W  = (size_t)2 * NBKT * ABLK;    //   391,000
    const size_t BN_W   = (size_t)2 * NBKT;           //       782
    const size_t need   = RECB_W + NODE_W + TABT_W + TAB_W + BN_W; // 34.76 MB

    if (ws_size >= need * 4) {
        unsigned* recB = (unsigned*)d_ws;
        float* fws    = (float*)d_ws + RECB_W;
        float* dinv_d = fws;
        float* dinv_g = fws + 1 * N_NODES;
        float* xs_d   = fws + 2 * N_NODES;
        float* xs_g   = fws + 3 * N_NODES;            // [2N] float2
        float* tt_d   = fws + 5 * N_NODES;
        float* tt_g   = fws + 6 * N_NODES;
        int* tabT = (int*)d_ws + RECB_W + NODE_W;
        int* np   = tabT;                             // alias (tabT dead post-kScan)
        int* tab  = tabT + TABT_W;
        int* bn   = tab + TAB_W;

        dim3 gA(ABLK, 2), gS(NBKT, 2), gB(NBKT, 2);
        kH    <<<gA, 256, 0, stream>>>(ei_d, ei_g, tabT);
        kScan <<<gS, 512, 0, stream>>>(tabT, tab, bn);
        kA2   <<<gA, 256, 0, stream>>>(ei_d, ei_g, tab, recB);
        kSort2<<<gB, 512, 0, stream>>>(recB, bn, np, x_d, (const float2*)x_g,
                                       dinv_d, dinv_g, xs_d, (float2*)xs_g);
        kP1   <<<gB, 256, 0, stream>>>(recB, np, dinv_d, dinv_g,
                                       xs_d, (const float2*)xs_g,
                                       W1_d, b1_d, W2_d, W1_g, b1_g, W2_g,
                                       tt_d, tt_g);
        kP2   <<<gB, 256, 0, stream>>>(recB, np, dinv_d, dinv_g, tt_d, tt_g,
                                       b2_d, b2_g, out);
        return;
    }

    // fallback: R1 scattered-atomic path (correct, slower)
    const int* src_d = ei_d;
    const int* dst_d = ei_d + N_EDGE;
    const int* src_g = ei_g;
    const int* dst_g = ei_g + N_EDGE;

    float* ws     = (float*)d_ws;
    float* dinv_d = ws;
    float* dinv_g = ws + 1 * N_NODES;
    float* s_d    = ws + 2 * N_NODES;
    float* s_g    = ws + 3 * N_NODES;
    float* xs_d   = ws + 5 * N_NODES;
    float* xs_g   = ws + 6 * N_NODES;

    hipMemsetAsync(ws, 0, (size_t)5 * N_NODES * sizeof(float), stream);
    hipMemsetAsync(d_out, 0, (size_t)2 * N_NODES * sizeof(float), stream);

    const int EB = (E4 + 255) / 256;
    const int NB = (N_NODES + 255) / 256;

    k_deg<<<EB, 256, 0, stream>>>((const int4*)dst_d, (const int4*)dst_g,
                                  dinv_d, dinv_g);
    k_dinv<<<NB, 256, 0, stream>>>(dinv_d, dinv_g, x_d, (const float2*)x_g,
                                   xs_d, (float2*)xs_g);
    k_prop1<<<EB, 256, 0, stream>>>((const int4*)src_d, (const int4*)dst_d,
                                    (const int4*)src_g, (const int4*)dst_g,
                                    xs_d, (const float2*)xs_g,
                                    s_d, (float2*)s_g);
    k_node<<<NB, 256, 0, stream>>>(dinv_d, dinv_g, s_d, (float2*)s_g,
                                   W1_d, b1_d, W2_d, W1_g, b1_g, W2_g);
    k_prop2<<<EB, 256, 0, stream>>>((const int4*)src_d, (const int4*)dst_d,
                                    (const int4*)src_g, (const int4*)dst_g,
                                    s_d, s_g, out);
    k_final<<<NB, 256, 0, stream>>>(out, dinv_d, dinv_g, b2_d, b2_g);
}

// Round 7
// 136.090 us; speedup vs baseline: 1.3069x; 1.1179x over previous
//
#include <hip/hip_runtime.h>

// HeteroVGAEEncoder: 2-layer GCN on two independent graphs (disease, gene).
// R7: kP1/kP2 were cache-invariant at ~54us with 12 waves/CU and 64-distinct-
// line vector loads (one thread per node). Split each node's CSR segment
// across 4 threads (stride-4) + __shfl_xor quad reduce: 4x waves for latency
// hiding, ~4x fewer distinct lines per row-load instruction.
// Pipeline (verified R6): kH chunk histograms -> kScan bucket scan -> kA2
// counting-sort scatter (bucket-major rows) -> kSort2 per-row node sort (CSR
// offsets + dinv/xs epilogue) -> kP1 per-node gather-sum + MLP -> kP2
// per-node gather-sum + bias. Zero global atomics anywhere.
// Algebraic collapse (verified R1-R6): GCN is linear -> propagate 1 (disease)
// / 2 (gene) scalars; fold dinv[dst] out of edge passes; 32-wide MLP node-wise.

static constexpr int N_NODES = 100000;
static constexpr int N_EDGE  = 3200000;
static constexpr int E4      = N_EDGE / 4;

static constexpr int NPB   = 256;                        // nodes per bucket
static constexpr int NBKT  = (N_NODES + NPB - 1) / NPB;  // 391
static constexpr int NBIN  = 392;                        // hist bins (last: 0)
static constexpr int CHUNK = 6400;                       // edges per A-chunk
static constexpr int ABLK  = N_EDGE / CHUNK;             // 500 (exact)
static constexpr int CAP_B = 9216;  // bucket row capacity (mean 8184, sd 90)
static constexpr unsigned SRC_MASK = 0x1FFFFu;           // 17 bits

// ============================== fast path =================================

// ---- kH: per-chunk bucket histogram (counts blk-major, coalesced) ----------
__global__ __launch_bounds__(256) void kH(
    const int* __restrict__ ei_d, const int* __restrict__ ei_g,
    int* __restrict__ tabT)                       // [2][ABLK][NBIN]
{
    __shared__ int hist[NBIN];
    const int g = blockIdx.y, blk = blockIdx.x, t = threadIdx.x;
    const int* dst = (g ? ei_g : ei_d) + N_EDGE + blk * CHUNK;
    for (int i = t; i < NBIN; i += 256) hist[i] = 0;
    __syncthreads();
    for (int e = t * 4; e < CHUNK; e += 1024) {
        int4 d4 = *(const int4*)(dst + e);
        atomicAdd(&hist[d4.x >> 8], 1);
        atomicAdd(&hist[d4.y >> 8], 1);
        atomicAdd(&hist[d4.z >> 8], 1);
        atomicAdd(&hist[d4.w >> 8], 1);
    }
    __syncthreads();
    int* row = tabT + (g * ABLK + blk) * NBIN;
    for (int i = t; i < NBIN; i += 256) row[i] = hist[i];
}

// ---- kScan: per-bucket exclusive scan over chunk counts --------------------
__global__ __launch_bounds__(512) void kScan(
    const int* __restrict__ tabT,                 // [2][ABLK][NBIN]
    int* __restrict__ tab,                        // [2][NBKT][ABLK]
    int* __restrict__ bn)                         // [2][NBKT]
{
    __shared__ int sc[512];
    const int g = blockIdx.y, b = blockIdx.x, t = threadIdx.x;
    int c = 0;
    if (t < ABLK) c = tabT[(g * ABLK + t) * NBIN + b];   // strided; L2-resident
    sc[t] = c;
    __syncthreads();
    for (int d = 1; d < 512; d <<= 1) {
        int add = (t >= d) ? sc[t - d] : 0;
        __syncthreads();
        sc[t] += add;
        __syncthreads();
    }
    if (t < ABLK) tab[(g * NBKT + b) * ABLK + t] = sc[t] - c;  // exclusive
    if (t == 511) bn[g * NBKT + b] = sc[511];
}

// ---- kA2: per-chunk counting sort, scatter segments to global slots --------
__global__ __launch_bounds__(256) void kA2(
    const int* __restrict__ ei_d, const int* __restrict__ ei_g,
    const int* __restrict__ tab,
    unsigned* __restrict__ recB)                  // [2][NBKT][CAP_B]
{
    __shared__ int hist[NBIN];
    __shared__ int sstart[NBIN];
    __shared__ int offs[NBIN];
    __shared__ int scanbuf[256];
    __shared__ unsigned stage[CHUNK];
    const int g = blockIdx.y, blk = blockIdx.x, t = threadIdx.x;
    const int* src = (g ? ei_g : ei_d) + blk * CHUNK;
    const int* dst = (g ? ei_g : ei_d) + N_EDGE + blk * CHUNK;

    for (int i = t; i < NBIN; i += 256) hist[i] = 0;
    __syncthreads();

    for (int e = t * 4; e < CHUNK; e += 1024) {
        int4 d4 = *(const int4*)(dst + e);
        atomicAdd(&hist[d4.x >> 8], 1);
        atomicAdd(&hist[d4.y >> 8], 1);
        atomicAdd(&hist[d4.z >> 8], 1);
        atomicAdd(&hist[d4.w >> 8], 1);
    }
    __syncthreads();

    int c0 = (2 * t < NBIN) ? hist[2 * t] : 0;
    int c1 = (2 * t + 1 < NBIN) ? hist[2 * t + 1] : 0;
    scanbuf[t] = c0 + c1;
    __syncthreads();
    for (int d = 1; d < 256; d <<= 1) {
        int add = (t >= d) ? scanbuf[t - d] : 0;
        __syncthreads();
        scanbuf[t] += add;
        __syncthreads();
    }
    int excl = t ? scanbuf[t - 1] : 0;
    if (2 * t < NBIN)     { sstart[2 * t] = excl;          offs[2 * t] = excl; }
    if (2 * t + 1 < NBIN) { sstart[2 * t + 1] = excl + c0; offs[2 * t + 1] = excl + c0; }
    __syncthreads();

    for (int e = t * 4; e < CHUNK; e += 1024) {
        int4 s4 = *(const int4*)(src + e);
        int4 d4 = *(const int4*)(dst + e);
        int p;
        p = atomicAdd(&offs[d4.x >> 8], 1);
        stage[p] = ((unsigned)(d4.x & 255) << 17) | (unsigned)s4.x;
        p = atomicAdd(&offs[d4.y >> 8], 1);
        stage[p] = ((unsigned)(d4.y & 255) << 17) | (unsigned)s4.y;
        p = atomicAdd(&offs[d4.z >> 8], 1);
        stage[p] = ((unsigned)(d4.z & 255) << 17) | (unsigned)s4.z;
        p = atomicAdd(&offs[d4.w >> 8], 1);
        stage[p] = ((unsigned)(d4.w & 255) << 17) | (unsigned)s4.w;
    }
    __syncthreads();

    // copy each bucket-segment to its exact global slot (16-lane groups)
    const int grp = t >> 4, ln = t & 15;
    for (int b = grp; b < NBKT; b += 16) {
        int s0 = sstart[b];
        int len = offs[b] - s0;
        if (len == 0) continue;
        int gpos = tab[(g * NBKT + b) * ABLK + blk];
        unsigned* dp = recB + ((size_t)(g * NBKT + b)) * CAP_B + gpos;
        for (int i = ln; i < len; i += 16)
            if (gpos + i < CAP_B) dp[i] = stage[s0 + i];
    }
}

// ---- kSort2: sort row by node, emit CSR offsets + dinv + xs ----------------
__global__ __launch_bounds__(512) void kSort2(
    unsigned* __restrict__ recB, const int* __restrict__ bn,
    int* __restrict__ np,                         // [2][NBKT][257]
    const float* __restrict__ x_d, const float2* __restrict__ x_g,
    float* __restrict__ dinv_d, float* __restrict__ dinv_g,
    float* __restrict__ xs_d, float2* __restrict__ xs_g)
{
    __shared__ int h2[256];
    __shared__ int sc[512];
    __shared__ int cur[256];
    __shared__ unsigned stg[CAP_B];
    const int g = blockIdx.y, b = blockIdx.x, t = threadIdx.x;
    if (t < 256) h2[t] = 0;
    __syncthreads();
    const int rowi = g * NBKT + b;
    unsigned* row = recB + (size_t)rowi * CAP_B;
    const int n = min(bn[rowi], CAP_B);

    for (int i = t; i < n; i += 512)
        atomicAdd(&h2[(row[i] >> 17) & 255], 1);
    __syncthreads();

    int c = (t < 256) ? h2[t] : 0;
    sc[t] = c;
    __syncthreads();
    for (int d = 1; d < 256; d <<= 1) {
        int add = (t >= d) ? sc[t - d] : 0;
        __syncthreads();
        sc[t] += add;
        __syncthreads();
    }
    if (t < 256) {
        int excl = sc[t] - c;
        cur[t] = excl;
        np[rowi * 257 + t] = excl;
    }
    if (t == 0) np[rowi * 257 + 256] = n;
    __syncthreads();

    for (int i = t; i < n; i += 512) {
        unsigned r = row[i];
        int p = atomicAdd(&cur[(r >> 17) & 255], 1);
        stg[p] = r;
    }
    __syncthreads();
    for (int i = t; i < n; i += 512) row[i] = stg[i];

    // epilogue: degree is h2[t] -> dinv, pre-scaled features
    if (t < 256) {
        int node = (b << 8) + t;
        if (node < N_NODES) {
            int deg = h2[t];
            float v = deg > 0 ? rsqrtf((float)deg) : 0.0f;
            if (g == 0) {
                dinv_d[node] = v;
                xs_d[node] = x_d[node] * v;
            } else {
                dinv_g[node] = v;
                float2 xg = x_g[node];
                xs_g[node] = make_float2(xg.x * v, xg.y * v);
            }
        }
    }
}

// ---- kP1: per-node (4-way split) gather-sum + MLP -> tt --------------------
__global__ __launch_bounds__(256) void kP1(
    const unsigned* __restrict__ recB, const int* __restrict__ np,
    const float* __restrict__ dinv_d, const float* __restrict__ dinv_g,
    const float* __restrict__ xs_d, const float2* __restrict__ xs_g,
    const float* __restrict__ W1_d, const float* __restrict__ b1_d,
    const float* __restrict__ W2_d,
    const float* __restrict__ W1_g, const float* __restrict__ b1_g,
    const float* __restrict__ W2_g,
    float* __restrict__ tt_d, float* __restrict__ tt_g)
{
    const int g = blockIdx.y;
    const int tid = blockIdx.x * 256 + threadIdx.x;
    const int node = tid >> 2, part = tid & 3;
    if (node >= N_NODES) return;
    const int b = node >> 8, l = node & 255;
    const int rowi = g * NBKT + b;
    const unsigned* row = recB + (size_t)rowi * CAP_B;
    const int s = np[rowi * 257 + l];
    const int e = np[rowi * 257 + l + 1];
    if (g == 0) {
        float a0 = 0.0f;
        for (int i = s + part; i < e; i += 4)
            a0 += xs_d[row[i] & SRC_MASK];
        // quad reduce (parts of a node are adjacent lanes)
        a0 += __shfl_xor(a0, 1);
        a0 += __shfl_xor(a0, 2);
        if (part == 0) {
            float v = dinv_d[node];
            float sf = a0 * v;
            float a = 0.0f;
#pragma unroll
            for (int k = 0; k < 32; ++k)
                a += fmaxf(sf * W1_d[k] + b1_d[k], 0.0f) * W2_d[k];
            tt_d[node] = a * v;
        }
    } else {
        float ax = 0.0f, ay = 0.0f;
        for (int i = s + part; i < e; i += 4) {
            float2 xv = xs_g[row[i] & SRC_MASK];
            ax += xv.x; ay += xv.y;
        }
        ax += __shfl_xor(ax, 1); ay += __shfl_xor(ay, 1);
        ax += __shfl_xor(ax, 2); ay += __shfl_xor(ay, 2);
        if (part == 0) {
            float v = dinv_g[node];
            float sf0 = ax * v;
            float sf1 = ay * v;
            float a = 0.0f;
#pragma unroll
            for (int k = 0; k < 32; ++k)
                a += fmaxf(sf0 * W1_g[k] + sf1 * W1_g[32 + k] + b1_g[k], 0.0f) * W2_g[k];
            tt_g[node] = a * v;
        }
    }
}

// ---- kP2: per-node (4-way split) gather-sum -> out = sum*dinv + b2 ---------
__global__ __launch_bounds__(256) void kP2(
    const unsigned* __restrict__ recB, const int* __restrict__ np,
    const float* __restrict__ dinv_d, const float* __restrict__ dinv_g,
    const float* __restrict__ tt_d, const float* __restrict__ tt_g,
    const float* __restrict__ b2_d, const float* __restrict__ b2_g,
    float* __restrict__ out)
{
    const int g = blockIdx.y;
    const int tid = blockIdx.x * 256 + threadIdx.x;
    const int node = tid >> 2, part = tid & 3;
    if (node >= N_NODES) return;
    const int b = node >> 8, l = node & 255;
    const int rowi = g * NBKT + b;
    const unsigned* row = recB + (size_t)rowi * CAP_B;
    const int s = np[rowi * 257 + l];
    const int e = np[rowi * 257 + l + 1];
    const float* tt = (g ? tt_g : tt_d);
    float a0 = 0.0f;
    for (int i = s + part; i < e; i += 4)
        a0 += tt[row[i] & SRC_MASK];
    a0 += __shfl_xor(a0, 1);
    a0 += __shfl_xor(a0, 2);
    if (part == 0) {
        float v = (g ? dinv_g : dinv_d)[node];
        float bias = (g ? b2_g : b2_d)[0];
        out[g * N_NODES + node] = a0 * v + bias;
    }
}

// ============================ fallback path (R1) ===========================

__global__ __launch_bounds__(256) void k_deg(
    const int4* __restrict__ dst_d, const int4* __restrict__ dst_g,
    float* __restrict__ deg_d, float* __restrict__ deg_g)
{
    int tid = blockIdx.x * 256 + threadIdx.x;
    int stride = gridDim.x * 256;
    for (int e = tid; e < E4; e += stride) {
        int4 a = dst_d[e];
        int4 b = dst_g[e];
        atomicAdd(&deg_d[a.x], 1.0f); atomicAdd(&deg_d[a.y], 1.0f);
        atomicAdd(&deg_d[a.z], 1.0f); atomicAdd(&deg_d[a.w], 1.0f);
        atomicAdd(&deg_g[b.x], 1.0f); atomicAdd(&deg_g[b.y], 1.0f);
        atomicAdd(&deg_g[b.z], 1.0f); atomicAdd(&deg_g[b.w], 1.0f);
    }
}

__global__ __launch_bounds__(256) void k_dinv(
    float* __restrict__ dinv_d, float* __restrict__ dinv_g,
    const float* __restrict__ x_d, const float2* __restrict__ x_g,
    float* __restrict__ xs_d, float2* __restrict__ xs_g)
{
    int i = blockIdx.x * 256 + threadIdx.x;
    int stride = gridDim.x * 256;
    for (; i < N_NODES; i += stride) {
        float dd = dinv_d[i];
        float vd = dd > 0.0f ? rsqrtf(dd) : 0.0f;
        dinv_d[i] = vd;
        xs_d[i] = x_d[i] * vd;
        float dg = dinv_g[i];
        float vg = dg > 0.0f ? rsqrtf(dg) : 0.0f;
        dinv_g[i] = vg;
        float2 xg = x_g[i];
        xs_g[i] = make_float2(xg.x * vg, xg.y * vg);
    }
}

__global__ __launch_bounds__(256) void k_prop1(
    const int4* __restrict__ src_d, const int4* __restrict__ dst_d,
    const int4* __restrict__ src_g, const int4* __restrict__ dst_g,
    const float* __restrict__ xs_d, const float2* __restrict__ xs_g,
    float* __restrict__ s_d, float2* __restrict__ s_g)
{
    int tid = blockIdx.x * 256 + threadIdx.x;
    int stride = gridDim.x * 256;
    for (int e = tid; e < E4; e += stride) {
        int4 sa = src_d[e]; int4 da = dst_d[e];
        int4 sb = src_g[e]; int4 db = dst_g[e];
        atomicAdd(&s_d[da.x], xs_d[sa.x]);
        atomicAdd(&s_d[da.y], xs_d[sa.y]);
        atomicAdd(&s_d[da.z], xs_d[sa.z]);
        atomicAdd(&s_d[da.w], xs_d[sa.w]);
        float2 g0 = xs_g[sb.x]; float2 g1 = xs_g[sb.y];
        float2 g2 = xs_g[sb.z]; float2 g3 = xs_g[sb.w];
        atomicAdd(&s_g[db.x].x, g0.x); atomicAdd(&s_g[db.x].y, g0.y);
        atomicAdd(&s_g[db.y].x, g1.x); atomicAdd(&s_g[db.y].y, g1.y);
        atomicAdd(&s_g[db.z].x, g2.x); atomicAdd(&s_g[db.z].y, g2.y);
        atomicAdd(&s_g[db.w].x, g3.x); atomicAdd(&s_g[db.w].y, g3.y);
    }
}

__global__ __launch_bounds__(256) void k_node(
    const float* __restrict__ dinv_d, const float* __restrict__ dinv_g,
    float* s_d, float2* s_g,
    const float* __restrict__ W1_d, const float* __restrict__ b1_d,
    const float* __restrict__ W2_d,
    const float* __restrict__ W1_g, const float* __restrict__ b1_g,
    const float* __restrict__ W2_g)
{
    int i = blockIdx.x * 256 + threadIdx.x;
    int stride = gridDim.x * 256;
    for (; i < N_NODES; i += stride) {
        float vd = dinv_d[i];
        float sd = s_d[i] * vd;
        float acc_d = 0.0f;
#pragma unroll
        for (int k = 0; k < 32; ++k)
            acc_d += fmaxf(sd * W1_d[k] + b1_d[k], 0.0f) * W2_d[k];
        s_d[i] = acc_d * vd;
        float vg = dinv_g[i];
        float2 sg = s_g[i];
        float s0 = sg.x * vg;
        float s1 = sg.y * vg;
        float acc_g = 0.0f;
#pragma unroll
        for (int k = 0; k < 32; ++k)
            acc_g += fmaxf(s0 * W1_g[k] + s1 * W1_g[32 + k] + b1_g[k], 0.0f) * W2_g[k];
        s_g[i].x = acc_g * vg;
    }
}

__global__ __launch_bounds__(256) void k_prop2(
    const int4* __restrict__ src_d, const int4* __restrict__ dst_d,
    const int4* __restrict__ src_g, const int4* __restrict__ dst_g,
    const float* __restrict__ tt_d, const float* __restrict__ tt_g2,
    float* __restrict__ out)
{
    int tid = blockIdx.x * 256 + threadIdx.x;
    int stride = gridDim.x * 256;
    for (int e = tid; e < E4; e += stride) {
        int4 sa = src_d[e]; int4 da = dst_d[e];
        int4 sb = src_g[e]; int4 db = dst_g[e];
        atomicAdd(&out[da.x], tt_d[sa.x]);
        atomicAdd(&out[da.y], tt_d[sa.y]);
        atomicAdd(&out[da.z], tt_d[sa.z]);
        atomicAdd(&out[da.w], tt_d[sa.w]);
        atomicAdd(&out[N_NODES + db.x], tt_g2[2 * sb.x]);
        atomicAdd(&out[N_NODES + db.y], tt_g2[2 * sb.y]);
        atomicAdd(&out[N_NODES + db.z], tt_g2[2 * sb.z]);
        atomicAdd(&out[N_NODES + db.w], tt_g2[2 * sb.w]);
    }
}

__global__ __launch_bounds__(256) void k_final(
    float* __restrict__ out,
    const float* __restrict__ dinv_d, const float* __restrict__ dinv_g,
    const float* __restrict__ b2_d, const float* __restrict__ b2_g)
{
    int i = blockIdx.x * 256 + threadIdx.x;
    int stride = gridDim.x * 256;
    float bd = b2_d[0];
    float bg = b2_g[0];
    for (; i < N_NODES; i += stride) {
        out[i] = out[i] * dinv_d[i] + bd;
        out[N_NODES + i] = out[N_NODES + i] * dinv_g[i] + bg;
    }
}

// ================================ launch ===================================

extern "C" void kernel_launch(void* const* d_in, const int* in_sizes, int n_in,
                              void* d_out, int out_size, void* d_ws, size_t ws_size,
                              hipStream_t stream) {
    const float* x_d  = (const float*)d_in[0];
    const float* x_g  = (const float*)d_in[1];
    const int*   ei_d = (const int*)d_in[2];
    const int*   ei_g = (const int*)d_in[3];
    const float* W1_d = (const float*)d_in[4];
    const float* b1_d = (const float*)d_in[5];
    const float* W1_g = (const float*)d_in[6];
    const float* b1_g = (const float*)d_in[7];
    const float* W2_d = (const float*)d_in[8];
    const float* b2_d = (const float*)d_in[9];
    const float* W2_g = (const float*)d_in[10];
    const float* b2_g = (const float*)d_in[11];
    float* out = (float*)d_out;

    // fast-path workspace layout (4B words); np ALIASES tabT (dead after kScan)
    const size_t RECB_W = (size_t)2 * NBKT * CAP_B;   // 7,206,912
    const size_t NODE_W = (size_t)7 * N_NODES;        //   700,000
    const size_t TABT_W = (size_t)2 * ABLK * NBIN;    //   392,000 (np: 200,974)
    const size_t TAB_W  = (size_t)2 * NBKT * ABLK;    //   391,000
    const size_t BN_W   = (size_t)2 * NBKT;           //       782
    const size_t need   = RECB_W + NODE_W + TABT_W + TAB_W + BN_W; // 34.76 MB

    if (ws_size >= need * 4) {
        unsigned* recB = (unsigned*)d_ws;
        float* fws    = (float*)d_ws + RECB_W;
        float* dinv_d = fws;
        float* dinv_g = fws + 1 * N_NODES;
        float* xs_d   = fws + 2 * N_NODES;
        float* xs_g   = fws + 3 * N_NODES;            // [2N] float2
        float* tt_d   = fws + 5 * N_NODES;
        float* tt_g   = fws + 6 * N_NODES;
        int* tabT = (int*)d_ws + RECB_W + NODE_W;
        int* np   = tabT;                             // alias (tabT dead post-kScan)
        int* tab  = tabT + TABT_W;
        int* bn   = tab + TAB_W;

        dim3 gA(ABLK, 2), gS(NBKT, 2), gB(NBKT, 2);
        dim3 gP(((size_t)N_NODES * 4 + 255) / 256, 2);   // 1563 x 2
        kH    <<<gA, 256, 0, stream>>>(ei_d, ei_g, tabT);
        kScan <<<gS, 512, 0, stream>>>(tabT, tab, bn);
        kA2   <<<gA, 256, 0, stream>>>(ei_d, ei_g, tab, recB);
        kSort2<<<gB, 512, 0, stream>>>(recB, bn, np, x_d, (const float2*)x_g,
                                       dinv_d, dinv_g, xs_d, (float2*)xs_g);
        kP1   <<<gP, 256, 0, stream>>>(recB, np, dinv_d, dinv_g,
                                       xs_d, (const float2*)xs_g,
                                       W1_d, b1_d, W2_d, W1_g, b1_g, W2_g,
                                       tt_d, tt_g);
        kP2   <<<gP, 256, 0, stream>>>(recB, np, dinv_d, dinv_g, tt_d, tt_g,
                                       b2_d, b2_g, out);
        return;
    }

    // fallback: R1 scattered-atomic path (correct, slower)
    const int* src_d = ei_d;
    const int* dst_d = ei_d + N_EDGE;
    const int* src_g = ei_g;
    const int* dst_g = ei_g + N_EDGE;

    float* ws     = (float*)d_ws;
    float* dinv_d = ws;
    float* dinv_g = ws + 1 * N_NODES;
    float* s_d    = ws + 2 * N_NODES;
    float* s_g    = ws + 3 * N_NODES;
    float* xs_d   = ws + 5 * N_NODES;
    float* xs_g   = ws + 6 * N_NODES;

    hipMemsetAsync(ws, 0, (size_t)5 * N_NODES * sizeof(float), stream);
    hipMemsetAsync(d_out, 0, (size_t)2 * N_NODES * sizeof(float), stream);

    const int EB = (E4 + 255) / 256;
    const int NB = (N_NODES + 255) / 256;

    k_deg<<<EB, 256, 0, stream>>>((const int4*)dst_d, (const int4*)dst_g,
                                  dinv_d, dinv_g);
    k_dinv<<<NB, 256, 0, stream>>>(dinv_d, dinv_g, x_d, (const float2*)x_g,
                                   xs_d, (float2*)xs_g);
    k_prop1<<<EB, 256, 0, stream>>>((const int4*)src_d, (const int4*)dst_d,
                                    (const int4*)src_g, (const int4*)dst_g,
                                    xs_d, (const float2*)xs_g,
                                    s_d, (float2*)s_g);
    k_node<<<NB, 256, 0, stream>>>(dinv_d, dinv_g, s_d, (float2*)s_g,
                                   W1_d, b1_d, W2_d, W1_g, b1_g, W2_g);
    k_prop2<<<EB, 256, 0, stream>>>((const int4*)src_d, (const int4*)dst_d,
                                    (const int4*)src_g, (const int4*)dst_g,
                                    s_d, s_g, out);
    k_final<<<NB, 256, 0, stream>>>(out, dinv_d, dinv_g, b2_d, b2_g);
}

// Round 8
// 127.433 us; speedup vs baseline: 1.3957x; 1.0679x over previous
//
#include <hip/hip_runtime.h>

// HeteroVGAEEncoder: 2-layer GCN on two independent graphs (disease, gene).
// R8: prop passes become two-phase block kernels over HALF-ROWS (128 nodes):
//   phase A: 512 thr stream sorted records coalesced + 4-batched random
//            gathers -> swizzled LDS value stage (no atomics, max TLP x ILP)
//   phase B: quad-per-node sums FROM LDS (2-way bank alias = free), shfl
//            reduce, MLP/bias, write.
// R7 evidence: per-node CSR gather loop is latency-bound (cache-invariant
// 42us, 53% occupancy) -- the segment structure caps TLP and ILP. Staging
// decouples gather issue (position-parallel) from per-node reduction (LDS).
// Pipeline (proven R6/R7): kH chunk histograms -> kScan bucket scan -> kA2
// counting-sort scatter (bucket-major rows) -> kSort2 per-row node sort (CSR
// np + dinv + xs) -> kP1F -> kP2F. Zero global atomics anywhere.
// Algebraic collapse (verified R1-R7): GCN is linear -> propagate 1 (disease)
// / 2 (gene) scalars; fold dinv[dst] out of edge passes; 32-wide MLP node-wise.

static constexpr int N_NODES = 100000;
static constexpr int N_EDGE  = 3200000;
static constexpr int E4      = N_EDGE / 4;

static constexpr int NPB   = 256;                        // nodes per bucket
static constexpr int NBKT  = (N_NODES + NPB - 1) / NPB;  // 391
static constexpr int NBIN  = 392;                        // hist bins (last: 0)
static constexpr int CHUNK = 6400;                       // edges per A-chunk
static constexpr int ABLK  = N_EDGE / CHUNK;             // 500 (exact)
static constexpr int CAP_B = 9216;  // bucket row capacity (mean 8184, sd 90)
static constexpr unsigned SRC_MASK = 0x1FFFFu;           // 17 bits

static constexpr int HNPB = 128;    // nodes per half-row block
static constexpr int HCAP = 4800;   // half-row stage cap (mean 4096, 11 sigma)
static constexpr int LVSZ = HCAP + HCAP / 32 + 4;        // swizzled plane size

__device__ __forceinline__ int swz(int i) { return i + (i >> 5); }

// ============================== fast path =================================

// ---- kH: per-chunk bucket histogram (counts blk-major, coalesced) ----------
__global__ __launch_bounds__(256) void kH(
    const int* __restrict__ ei_d, const int* __restrict__ ei_g,
    int* __restrict__ tabT)                       // [2][ABLK][NBIN]
{
    __shared__ int hist[NBIN];
    const int g = blockIdx.y, blk = blockIdx.x, t = threadIdx.x;
    const int* dst = (g ? ei_g : ei_d) + N_EDGE + blk * CHUNK;
    for (int i = t; i < NBIN; i += 256) hist[i] = 0;
    __syncthreads();
    for (int e = t * 4; e < CHUNK; e += 1024) {
        int4 d4 = *(const int4*)(dst + e);
        atomicAdd(&hist[d4.x >> 8], 1);
        atomicAdd(&hist[d4.y >> 8], 1);
        atomicAdd(&hist[d4.z >> 8], 1);
        atomicAdd(&hist[d4.w >> 8], 1);
    }
    __syncthreads();
    int* row = tabT + (g * ABLK + blk) * NBIN;
    for (int i = t; i < NBIN; i += 256) row[i] = hist[i];
}

// ---- kScan: per-bucket exclusive scan over chunk counts --------------------
__global__ __launch_bounds__(512) void kScan(
    const int* __restrict__ tabT,                 // [2][ABLK][NBIN]
    int* __restrict__ tab,                        // [2][NBKT][ABLK]
    int* __restrict__ bn)                         // [2][NBKT]
{
    __shared__ int sc[512];
    const int g = blockIdx.y, b = blockIdx.x, t = threadIdx.x;
    int c = 0;
    if (t < ABLK) c = tabT[(g * ABLK + t) * NBIN + b];   // strided; L2-resident
    sc[t] = c;
    __syncthreads();
    for (int d = 1; d < 512; d <<= 1) {
        int add = (t >= d) ? sc[t - d] : 0;
        __syncthreads();
        sc[t] += add;
        __syncthreads();
    }
    if (t < ABLK) tab[(g * NBKT + b) * ABLK + t] = sc[t] - c;  // exclusive
    if (t == 511) bn[g * NBKT + b] = sc[511];
}

// ---- kA2: per-chunk counting sort, scatter segments to global slots --------
__global__ __launch_bounds__(256) void kA2(
    const int* __restrict__ ei_d, const int* __restrict__ ei_g,
    const int* __restrict__ tab,
    unsigned* __restrict__ recB)                  // [2][NBKT][CAP_B]
{
    __shared__ int hist[NBIN];
    __shared__ int sstart[NBIN];
    __shared__ int offs[NBIN];
    __shared__ int scanbuf[256];
    __shared__ unsigned stage[CHUNK];
    const int g = blockIdx.y, blk = blockIdx.x, t = threadIdx.x;
    const int* src = (g ? ei_g : ei_d) + blk * CHUNK;
    const int* dst = (g ? ei_g : ei_d) + N_EDGE + blk * CHUNK;

    for (int i = t; i < NBIN; i += 256) hist[i] = 0;
    __syncthreads();

    for (int e = t * 4; e < CHUNK; e += 1024) {
        int4 d4 = *(const int4*)(dst + e);
        atomicAdd(&hist[d4.x >> 8], 1);
        atomicAdd(&hist[d4.y >> 8], 1);
        atomicAdd(&hist[d4.z >> 8], 1);
        atomicAdd(&hist[d4.w >> 8], 1);
    }
    __syncthreads();

    int c0 = (2 * t < NBIN) ? hist[2 * t] : 0;
    int c1 = (2 * t + 1 < NBIN) ? hist[2 * t + 1] : 0;
    scanbuf[t] = c0 + c1;
    __syncthreads();
    for (int d = 1; d < 256; d <<= 1) {
        int add = (t >= d) ? scanbuf[t - d] : 0;
        __syncthreads();
        scanbuf[t] += add;
        __syncthreads();
    }
    int excl = t ? scanbuf[t - 1] : 0;
    if (2 * t < NBIN)     { sstart[2 * t] = excl;          offs[2 * t] = excl; }
    if (2 * t + 1 < NBIN) { sstart[2 * t + 1] = excl + c0; offs[2 * t + 1] = excl + c0; }
    __syncthreads();

    for (int e = t * 4; e < CHUNK; e += 1024) {
        int4 s4 = *(const int4*)(src + e);
        int4 d4 = *(const int4*)(dst + e);
        int p;
        p = atomicAdd(&offs[d4.x >> 8], 1);
        stage[p] = ((unsigned)(d4.x & 255) << 17) | (unsigned)s4.x;
        p = atomicAdd(&offs[d4.y >> 8], 1);
        stage[p] = ((unsigned)(d4.y & 255) << 17) | (unsigned)s4.y;
        p = atomicAdd(&offs[d4.z >> 8], 1);
        stage[p] = ((unsigned)(d4.z & 255) << 17) | (unsigned)s4.z;
        p = atomicAdd(&offs[d4.w >> 8], 1);
        stage[p] = ((unsigned)(d4.w & 255) << 17) | (unsigned)s4.w;
    }
    __syncthreads();

    // copy each bucket-segment to its exact global slot (16-lane groups)
    const int grp = t >> 4, ln = t & 15;
    for (int b = grp; b < NBKT; b += 16) {
        int s0 = sstart[b];
        int len = offs[b] - s0;
        if (len == 0) continue;
        int gpos = tab[(g * NBKT + b) * ABLK + blk];
        unsigned* dp = recB + ((size_t)(g * NBKT + b)) * CAP_B + gpos;
        for (int i = ln; i < len; i += 16)
            if (gpos + i < CAP_B) dp[i] = stage[s0 + i];
    }
}

// ---- kSort2: sort row by node, emit CSR offsets + dinv + xs ----------------
__global__ __launch_bounds__(512) void kSort2(
    unsigned* __restrict__ recB, const int* __restrict__ bn,
    int* __restrict__ np,                         // [2][NBKT][257]
    const float* __restrict__ x_d, const float2* __restrict__ x_g,
    float* __restrict__ dinv_d, float* __restrict__ dinv_g,
    float* __restrict__ xs_d, float2* __restrict__ xs_g)
{
    __shared__ int h2[256];
    __shared__ int sc[512];
    __shared__ int cur[256];
    __shared__ unsigned stg[CAP_B];
    const int g = blockIdx.y, b = blockIdx.x, t = threadIdx.x;
    if (t < 256) h2[t] = 0;
    __syncthreads();
    const int rowi = g * NBKT + b;
    unsigned* row = recB + (size_t)rowi * CAP_B;
    const int n = min(bn[rowi], CAP_B);

    for (int i = t; i < n; i += 512)
        atomicAdd(&h2[(row[i] >> 17) & 255], 1);
    __syncthreads();

    int c = (t < 256) ? h2[t] : 0;
    sc[t] = c;
    __syncthreads();
    for (int d = 1; d < 256; d <<= 1) {
        int add = (t >= d) ? sc[t - d] : 0;
        __syncthreads();
        sc[t] += add;
        __syncthreads();
    }
    if (t < 256) {
        int excl = sc[t] - c;
        cur[t] = excl;
        np[rowi * 257 + t] = excl;
    }
    if (t == 0) np[rowi * 257 + 256] = n;
    __syncthreads();

    for (int i = t; i < n; i += 512) {
        unsigned r = row[i];
        int p = atomicAdd(&cur[(r >> 17) & 255], 1);
        stg[p] = r;
    }
    __syncthreads();
    for (int i = t; i < n; i += 512) row[i] = stg[i];

    // epilogue: degree is h2[t] -> dinv, pre-scaled features
    if (t < 256) {
        int node = (b << 8) + t;
        if (node < N_NODES) {
            int deg = h2[t];
            float v = deg > 0 ? rsqrtf((float)deg) : 0.0f;
            if (g == 0) {
                dinv_d[node] = v;
                xs_d[node] = x_d[node] * v;
            } else {
                dinv_g[node] = v;
                float2 xg = x_g[node];
                xs_g[node] = make_float2(xg.x * v, xg.y * v);
            }
        }
    }
}

// ---- kP1F: half-row staged gather + per-node LDS sum + MLP -> tt -----------
__global__ __launch_bounds__(512) void kP1F(
    const unsigned* __restrict__ recB, const int* __restrict__ np,
    const float* __restrict__ dinv_d, const float* __restrict__ dinv_g,
    const float* __restrict__ xs_d, const float2* __restrict__ xs_g,
    const float* __restrict__ W1_d, const float* __restrict__ b1_d,
    const float* __restrict__ W2_d,
    const float* __restrict__ W1_g, const float* __restrict__ b1_g,
    const float* __restrict__ W2_g,
    float* __restrict__ tt_d, float* __restrict__ tt_g)
{
    __shared__ float lv[2 * LVSZ];                // ~39.6 KB
    const int g = blockIdx.y;
    const int bkt = blockIdx.x >> 1, h = blockIdx.x & 1, t = threadIdx.x;
    const int rowi = g * NBKT + bkt;
    const int* npr = np + rowi * 257 + h * HNPB;
    const int base = npr[0];
    const int len = min(npr[HNPB] - base, HCAP);
    const unsigned* row = recB + (size_t)rowi * CAP_B + base;

    // phase A: stage values (coalesced record reads, 4-batched random gathers)
    if (g == 0) {
        int i = t;
        for (; i + 1536 < len; i += 2048) {
            unsigned r0 = row[i], r1 = row[i + 512], r2 = row[i + 1024], r3 = row[i + 1536];
            float v0 = xs_d[r0 & SRC_MASK];
            float v1 = xs_d[r1 & SRC_MASK];
            float v2 = xs_d[r2 & SRC_MASK];
            float v3 = xs_d[r3 & SRC_MASK];
            lv[swz(i)] = v0; lv[swz(i + 512)] = v1;
            lv[swz(i + 1024)] = v2; lv[swz(i + 1536)] = v3;
        }
        for (; i < len; i += 512) lv[swz(i)] = xs_d[row[i] & SRC_MASK];
    } else {
        int i = t;
        for (; i + 1536 < len; i += 2048) {
            unsigned r0 = row[i], r1 = row[i + 512], r2 = row[i + 1024], r3 = row[i + 1536];
            float2 v0 = xs_g[r0 & SRC_MASK];
            float2 v1 = xs_g[r1 & SRC_MASK];
            float2 v2 = xs_g[r2 & SRC_MASK];
            float2 v3 = xs_g[r3 & SRC_MASK];
            lv[swz(i)] = v0.x;        lv[LVSZ + swz(i)] = v0.y;
            lv[swz(i + 512)] = v1.x;  lv[LVSZ + swz(i + 512)] = v1.y;
            lv[swz(i + 1024)] = v2.x; lv[LVSZ + swz(i + 1024)] = v2.y;
            lv[swz(i + 1536)] = v3.x; lv[LVSZ + swz(i + 1536)] = v3.y;
        }
        for (; i < len; i += 512) {
            float2 v = xs_g[row[i] & SRC_MASK];
            lv[swz(i)] = v.x; lv[LVSZ + swz(i)] = v.y;
        }
    }
    __syncthreads();

    // phase B: quad-per-node sums from LDS + shfl reduce + MLP
    const int part = t & 3, tn = t >> 2;          // tn in [0,128)
    const int node = (bkt << 8) + h * HNPB + tn;
    int s = min(npr[tn] - base, len);
    int e = min(npr[tn + 1] - base, len);
    float a0 = 0.0f, a1 = 0.0f;
    if (g == 0) {
        for (int k = s + part; k < e; k += 4) a0 += lv[swz(k)];
    } else {
        for (int k = s + part; k < e; k += 4) {
            a0 += lv[swz(k)];
            a1 += lv[LVSZ + swz(k)];
        }
    }
    a0 += __shfl_xor(a0, 1); a0 += __shfl_xor(a0, 2);
    a1 += __shfl_xor(a1, 1); a1 += __shfl_xor(a1, 2);
    if (part == 0 && node < N_NODES) {
        if (g == 0) {
            float v = dinv_d[node];
            float sf = a0 * v;
            float a = 0.0f;
#pragma unroll
            for (int k = 0; k < 32; ++k)
                a += fmaxf(sf * W1_d[k] + b1_d[k], 0.0f) * W2_d[k];
            tt_d[node] = a * v;
        } else {
            float v = dinv_g[node];
            float sf0 = a0 * v;
            float sf1 = a1 * v;
            float a = 0.0f;
#pragma unroll
            for (int k = 0; k < 32; ++k)
                a += fmaxf(sf0 * W1_g[k] + sf1 * W1_g[32 + k] + b1_g[k], 0.0f) * W2_g[k];
            tt_g[node] = a * v;
        }
    }
}

// ---- kP2F: half-row staged gather (tt) + per-node LDS sum -> out -----------
__global__ __launch_bounds__(512) void kP2F(
    const unsigned* __restrict__ recB, const int* __restrict__ np,
    const float* __restrict__ dinv_d, const float* __restrict__ dinv_g,
    const float* __restrict__ tt_d, const float* __restrict__ tt_g,
    const float* __restrict__ b2_d, const float* __restrict__ b2_g,
    float* __restrict__ out)
{
    __shared__ float lv[LVSZ];                    // ~19.8 KB
    const int g = blockIdx.y;
    const int bkt = blockIdx.x >> 1, h = blockIdx.x & 1, t = threadIdx.x;
    const int rowi = g * NBKT + bkt;
    const int* npr = np + rowi * 257 + h * HNPB;
    const int base = npr[0];
    const int len = min(npr[HNPB] - base, HCAP);
    const unsigned* row = recB + (size_t)rowi * CAP_B + base;
    const float* tt = (g ? tt_g : tt_d);

    int i = t;
    for (; i + 1536 < len; i += 2048) {
        unsigned r0 = row[i], r1 = row[i + 512], r2 = row[i + 1024], r3 = row[i + 1536];
        float v0 = tt[r0 & SRC_MASK];
        float v1 = tt[r1 & SRC_MASK];
        float v2 = tt[r2 & SRC_MASK];
        float v3 = tt[r3 & SRC_MASK];
        lv[swz(i)] = v0; lv[swz(i + 512)] = v1;
        lv[swz(i + 1024)] = v2; lv[swz(i + 1536)] = v3;
    }
    for (; i < len; i += 512) lv[swz(i)] = tt[row[i] & SRC_MASK];
    __syncthreads();

    const int part = t & 3, tn = t >> 2;
    const int node = (bkt << 8) + h * HNPB + tn;
    int s = min(npr[tn] - base, len);
    int e = min(npr[tn + 1] - base, len);
    float a0 = 0.0f;
    for (int k = s + part; k < e; k += 4) a0 += lv[swz(k)];
    a0 += __shfl_xor(a0, 1); a0 += __shfl_xor(a0, 2);
    if (part == 0 && node < N_NODES) {
        float v = (g ? dinv_g : dinv_d)[node];
        float bias = (g ? b2_g : b2_d)[0];
        out[g * N_NODES + node] = a0 * v + bias;
    }
}

// ============================ fallback path (R1) ===========================

__global__ __launch_bounds__(256) void k_deg(
    const int4* __restrict__ dst_d, const int4* __restrict__ dst_g,
    float* __restrict__ deg_d, float* __restrict__ deg_g)
{
    int tid = blockIdx.x * 256 + threadIdx.x;
    int stride = gridDim.x * 256;
    for (int e = tid; e < E4; e += stride) {
        int4 a = dst_d[e];
        int4 b = dst_g[e];
        atomicAdd(&deg_d[a.x], 1.0f); atomicAdd(&deg_d[a.y], 1.0f);
        atomicAdd(&deg_d[a.z], 1.0f); atomicAdd(&deg_d[a.w], 1.0f);
        atomicAdd(&deg_g[b.x], 1.0f); atomicAdd(&deg_g[b.y], 1.0f);
        atomicAdd(&deg_g[b.z], 1.0f); atomicAdd(&deg_g[b.w], 1.0f);
    }
}

__global__ __launch_bounds__(256) void k_dinv(
    float* __restrict__ dinv_d, float* __restrict__ dinv_g,
    const float* __restrict__ x_d, const float2* __restrict__ x_g,
    float* __restrict__ xs_d, float2* __restrict__ xs_g)
{
    int i = blockIdx.x * 256 + threadIdx.x;
    int stride = gridDim.x * 256;
    for (; i < N_NODES; i += stride) {
        float dd = dinv_d[i];
        float vd = dd > 0.0f ? rsqrtf(dd) : 0.0f;
        dinv_d[i] = vd;
        xs_d[i] = x_d[i] * vd;
        float dg = dinv_g[i];
        float vg = dg > 0.0f ? rsqrtf(dg) : 0.0f;
        dinv_g[i] = vg;
        float2 xg = x_g[i];
        xs_g[i] = make_float2(xg.x * vg, xg.y * vg);
    }
}

__global__ __launch_bounds__(256) void k_prop1(
    const int4* __restrict__ src_d, const int4* __restrict__ dst_d,
    const int4* __restrict__ src_g, const int4* __restrict__ dst_g,
    const float* __restrict__ xs_d, const float2* __restrict__ xs_g,
    float* __restrict__ s_d, float2* __restrict__ s_g)
{
    int tid = blockIdx.x * 256 + threadIdx.x;
    int stride = gridDim.x * 256;
    for (int e = tid; e < E4; e += stride) {
        int4 sa = src_d[e]; int4 da = dst_d[e];
        int4 sb = src_g[e]; int4 db = dst_g[e];
        atomicAdd(&s_d[da.x], xs_d[sa.x]);
        atomicAdd(&s_d[da.y], xs_d[sa.y]);
        atomicAdd(&s_d[da.z], xs_d[sa.z]);
        atomicAdd(&s_d[da.w], xs_d[sa.w]);
        float2 g0 = xs_g[sb.x]; float2 g1 = xs_g[sb.y];
        float2 g2 = xs_g[sb.z]; float2 g3 = xs_g[sb.w];
        atomicAdd(&s_g[db.x].x, g0.x); atomicAdd(&s_g[db.x].y, g0.y);
        atomicAdd(&s_g[db.y].x, g1.x); atomicAdd(&s_g[db.y].y, g1.y);
        atomicAdd(&s_g[db.z].x, g2.x); atomicAdd(&s_g[db.z].y, g2.y);
        atomicAdd(&s_g[db.w].x, g3.x); atomicAdd(&s_g[db.w].y, g3.y);
    }
}

__global__ __launch_bounds__(256) void k_node(
    const float* __restrict__ dinv_d, const float* __restrict__ dinv_g,
    float* s_d, float2* s_g,
    const float* __restrict__ W1_d, const float* __restrict__ b1_d,
    const float* __restrict__ W2_d,
    const float* __restrict__ W1_g, const float* __restrict__ b1_g,
    const float* __restrict__ W2_g)
{
    int i = blockIdx.x * 256 + threadIdx.x;
    int stride = gridDim.x * 256;
    for (; i < N_NODES; i += stride) {
        float vd = dinv_d[i];
        float sd = s_d[i] * vd;
        float acc_d = 0.0f;
#pragma unroll
        for (int k = 0; k < 32; ++k)
            acc_d += fmaxf(sd * W1_d[k] + b1_d[k], 0.0f) * W2_d[k];
        s_d[i] = acc_d * vd;
        float vg = dinv_g[i];
        float2 sg = s_g[i];
        float s0 = sg.x * vg;
        float s1 = sg.y * vg;
        float acc_g = 0.0f;
#pragma unroll
        for (int k = 0; k < 32; ++k)
            acc_g += fmaxf(s0 * W1_g[k] + s1 * W1_g[32 + k] + b1_g[k], 0.0f) * W2_g[k];
        s_g[i].x = acc_g * vg;
    }
}

__global__ __launch_bounds__(256) void k_prop2(
    const int4* __restrict__ src_d, const int4* __restrict__ dst_d,
    const int4* __restrict__ src_g, const int4* __restrict__ dst_g,
    const float* __restrict__ tt_d, const float* __restrict__ tt_g2,
    float* __restrict__ out)
{
    int tid = blockIdx.x * 256 + threadIdx.x;
    int stride = gridDim.x * 256;
    for (int e = tid; e < E4; e += stride) {
        int4 sa = src_d[e]; int4 da = dst_d[e];
        int4 sb = src_g[e]; int4 db = dst_g[e];
        atomicAdd(&out[da.x], tt_d[sa.x]);
        atomicAdd(&out[da.y], tt_d[sa.y]);
        atomicAdd(&out[da.z], tt_d[sa.z]);
        atomicAdd(&out[da.w], tt_d[sa.w]);
        atomicAdd(&out[N_NODES + db.x], tt_g2[2 * sb.x]);
        atomicAdd(&out[N_NODES + db.y], tt_g2[2 * sb.y]);
        atomicAdd(&out[N_NODES + db.z], tt_g2[2 * sb.z]);
        atomicAdd(&out[N_NODES + db.w], tt_g2[2 * sb.w]);
    }
}

__global__ __launch_bounds__(256) void k_final(
    float* __restrict__ out,
    const float* __restrict__ dinv_d, const float* __restrict__ dinv_g,
    const float* __restrict__ b2_d, const float* __restrict__ b2_g)
{
    int i = blockIdx.x * 256 + threadIdx.x;
    int stride = gridDim.x * 256;
    float bd = b2_d[0];
    float bg = b2_g[0];
    for (; i < N_NODES; i += stride) {
        out[i] = out[i] * dinv_d[i] + bd;
        out[N_NODES + i] = out[N_NODES + i] * dinv_g[i] + bg;
    }
}

// ================================ launch ===================================

extern "C" void kernel_launch(void* const* d_in, const int* in_sizes, int n_in,
                              void* d_out, int out_size, void* d_ws, size_t ws_size,
                              hipStream_t stream) {
    const float* x_d  = (const float*)d_in[0];
    const float* x_g  = (const float*)d_in[1];
    const int*   ei_d = (const int*)d_in[2];
    const int*   ei_g = (const int*)d_in[3];
    const float* W1_d = (const float*)d_in[4];
    const float* b1_d = (const float*)d_in[5];
    const float* W1_g = (const float*)d_in[6];
    const float* b1_g = (const float*)d_in[7];
    const float* W2_d = (const float*)d_in[8];
    const float* b2_d = (const float*)d_in[9];
    const float* W2_g = (const float*)d_in[10];
    const float* b2_g = (const float*)d_in[11];
    float* out = (float*)d_out;

    // fast-path workspace layout (4B words); np ALIASES tabT (dead after kScan)
    const size_t RECB_W = (size_t)2 * NBKT * CAP_B;   // 7,206,912
    const size_t NODE_W = (size_t)7 * N_NODES;        //   700,000
    const size_t TABT_W = (size_t)2 * ABLK * NBIN;    //   392,000 (np: 200,974)
    const size_t TAB_W  = (size_t)2 * NBKT * ABLK;    //   391,000
    const size_t BN_W   = (size_t)2 * NBKT;           //       782
    const size_t need   = RECB_W + NODE_W + TABT_W + TAB_W + BN_W; // 34.76 MB

    if (ws_size >= need * 4) {
        unsigned* recB = (unsigned*)d_ws;
        float* fws    = (float*)d_ws + RECB_W;
        float* dinv_d = fws;
        float* dinv_g = fws + 1 * N_NODES;
        float* xs_d   = fws + 2 * N_NODES;
        float* xs_g   = fws + 3 * N_NODES;            // [2N] float2
        float* tt_d   = fws + 5 * N_NODES;
        float* tt_g   = fws + 6 * N_NODES;
        int* tabT = (int*)d_ws + RECB_W + NODE_W;
        int* np   = tabT;                             // alias (tabT dead post-kScan)
        int* tab  = tabT + TABT_W;
        int* bn   = tab + TAB_W;

        dim3 gA(ABLK, 2), gS(NBKT, 2), gB(NBKT, 2);
        dim3 gPF(NBKT * 2, 2);                        // half-row blocks
        kH    <<<gA, 256, 0, stream>>>(ei_d, ei_g, tabT);
        kScan <<<gS, 512, 0, stream>>>(tabT, tab, bn);
        kA2   <<<gA, 256, 0, stream>>>(ei_d, ei_g, tab, recB);
        kSort2<<<gB, 512, 0, stream>>>(recB, bn, np, x_d, (const float2*)x_g,
                                       dinv_d, dinv_g, xs_d, (float2*)xs_g);
        kP1F  <<<gPF, 512, 0, stream>>>(recB, np, dinv_d, dinv_g,
                                        xs_d, (const float2*)xs_g,
                                        W1_d, b1_d, W2_d, W1_g, b1_g, W2_g,
                                        tt_d, tt_g);
        kP2F  <<<gPF, 512, 0, stream>>>(recB, np, dinv_d, dinv_g, tt_d, tt_g,
                                        b2_d, b2_g, out);
        return;
    }

    // fallback: R1 scattered-atomic path (correct, slower)
    const int* src_d = ei_d;
    const int* dst_d = ei_d + N_EDGE;
    const int* src_g = ei_g;
    const int* dst_g = ei_g + N_EDGE;

    float* ws     = (float*)d_ws;
    float* dinv_d = ws;
    float* dinv_g = ws + 1 * N_NODES;
    float* s_d    = ws + 2 * N_NODES;
    float* s_g    = ws + 3 * N_NODES;
    float* xs_d   = ws + 5 * N_NODES;
    float* xs_g   = ws + 6 * N_NODES;

    hipMemsetAsync(ws, 0, (size_t)5 * N_NODES * sizeof(float), stream);
    hipMemsetAsync(d_out, 0, (size_t)2 * N_NODES * sizeof(float), stream);

    const int EB = (E4 + 255) / 256;
    const int NB = (N_NODES + 255) / 256;

    k_deg<<<EB, 256, 0, stream>>>((const int4*)dst_d, (const int4*)dst_g,
                                  dinv_d, dinv_g);
    k_dinv<<<NB, 256, 0, stream>>>(dinv_d, dinv_g, x_d, (const float2*)x_g,
                                   xs_d, (float2*)xs_g);
    k_prop1<<<EB, 256, 0, stream>>>((const int4*)src_d, (const int4*)dst_d,
                                    (const int4*)src_g, (const int4*)dst_g,
                                    xs_d, (const float2*)xs_g,
                                    s_d, (float2*)s_g);
    k_node<<<NB, 256, 0, stream>>>(dinv_d, dinv_g, s_d, (float2*)s_g,
                                   W1_d, b1_d, W2_d, W1_g, b1_g, W2_g);
    k_prop2<<<EB, 256, 0, stream>>>((const int4*)src_d, (const int4*)dst_d,
                                    (const int4*)src_g, (const int4*)dst_g,
                                    s_d, s_g, out);
    k_final<<<NB, 256, 0, stream>>>(out, dinv_d, dinv_g, b2_d, b2_g);
}